// Round 8
// baseline (439.973 us; speedup 1.0000x reference)
//
#include <hip/hip_runtime.h>
#include <hip/hip_bf16.h>
#include <cstdint>

#define E_DIM   1280
#define NHEADS  20
#define HDIM    64
#define QKV_LD  3840   // 3*E

typedef __attribute__((ext_vector_type(8))) short bf8_t;   // 8 bf16 (4 VGPRs)
typedef __attribute__((ext_vector_type(4))) short bf4_t;   // 4 bf16 (2 VGPRs)
typedef __attribute__((ext_vector_type(4))) float f4_t;    // MFMA accumulator

__device__ __forceinline__ short f2bs(float f) {
    union { __hip_bfloat16 h; short s; } u;
    u.h = __float2bfloat16(f);
    return u.s;
}

// hardware packed f32x2 -> bf16x2 (RNE), T12 recipe: no builtin on gfx950
__device__ __forceinline__ bf4_t pk4(f4_t s) {
    union { bf4_t v; uint32_t u[2]; } r;
    asm("v_cvt_pk_bf16_f32 %0, %1, %2" : "=v"(r.u[0]) : "v"(s[0]), "v"(s[1]));
    asm("v_cvt_pk_bf16_f32 %0, %1, %2" : "=v"(r.u[1]) : "v"(s[2]), "v"(s[3]));
    return r.v;
}

__device__ __forceinline__ f4_t mfma16x32(bf8_t a, bf8_t b, f4_t c) {
    return __builtin_amdgcn_mfma_f32_16x16x32_bf16(a, b, c, 0, 0, 0);
}
__device__ __forceinline__ f4_t mfma16x16(bf4_t a, bf4_t b, f4_t c) {
    return __builtin_amdgcn_mfma_f32_16x16x16bf16_1k(a, b, c, 0, 0, 0);
}

// async global->LDS, 16B per lane. LDS dest is wave-uniform base + lane*16.
__device__ __forceinline__ void gl_lds16(const void* g, void* l) {
    auto gp = reinterpret_cast<__attribute__((address_space(1))) unsigned int*>(
        reinterpret_cast<uintptr_t>(g));
    auto lp = reinterpret_cast<__attribute__((address_space(3))) unsigned int*>(
        reinterpret_cast<uintptr_t>(l));
    __builtin_amdgcn_global_load_lds(gp, lp, 16, 0, 0);
}

// ---------------- prep: casts + weight concat + bias concat ----------------
// Wq/bq scale = d^-0.5 * log2(e): softmax computed in base-2 domain (exp2f).
#define QSCALE 0.18033688011112042f

__device__ __forceinline__ void cvt8(__hip_bfloat16* dst, const float* src, float sc) {
    float4 a = *(const float4*)src;
    float4 b = *(const float4*)(src + 4);
    bf8_t v;
    v[0] = f2bs(a.x * sc); v[1] = f2bs(a.y * sc); v[2] = f2bs(a.z * sc); v[3] = f2bs(a.w * sc);
    v[4] = f2bs(b.x * sc); v[5] = f2bs(b.y * sc); v[6] = f2bs(b.z * sc); v[7] = f2bs(b.w * sc);
    *(bf8_t*)dst = v;
}

__global__ __launch_bounds__(256) void prep_kernel(
    const float* __restrict__ x,
    const float* __restrict__ wq, const float* __restrict__ wk,
    const float* __restrict__ wv, const float* __restrict__ wo,
    const float* __restrict__ bq, const float* __restrict__ bk, const float* __restrict__ bv,
    __hip_bfloat16* __restrict__ xbf, __hip_bfloat16* __restrict__ wqkv,
    __hip_bfloat16* __restrict__ wobf, float* __restrict__ bqkv,
    long nx8, long nw8, long nb8)
{
    long u = (long)blockIdx.x * 256 + threadIdx.x;
    if (u < nx8) { cvt8(xbf + u * 8, x + u * 8, 1.0f); return; }
    u -= nx8;
    if (u < 3 * nw8) {
        long e = u * 8;
        long w1 = nw8 * 8;
        const float* src; float sc;
        if (e < w1)            { src = wq + e;           sc = QSCALE; }
        else if (e < 2 * w1)   { src = wk + (e - w1);    sc = 1.0f; }
        else                   { src = wv + (e - 2*w1);  sc = 1.0f; }
        cvt8(wqkv + e, src, sc);
        return;
    }
    u -= 3 * nw8;
    if (u < nw8) { cvt8(wobf + u * 8, wo + u * 8, 1.0f); return; }
    u -= nw8;
    if (u < nb8) {
        long e = u * 8;
        #pragma unroll
        for (int j = 0; j < 8; j++) {
            long i = e + j;
            float v;
            if (i < E_DIM)           v = bq[i] * QSCALE;
            else if (i < 2 * E_DIM)  v = bk[i - E_DIM];
            else                     v = bv[i - 2 * E_DIM];
            bqkv[i] = v;
        }
    }
}

// ---------------- m97-style NT GEMM (output proj): C = A*B^T + bias ----------------
template<bool BF16_OUT>
__global__ __launch_bounds__(256, 3) void gemm_nt(
    const __hip_bfloat16* __restrict__ A, const __hip_bfloat16* __restrict__ Bw,
    const float* __restrict__ bias, void* __restrict__ Cout,
    int M, int N, int K, int ldc)
{
    __shared__ __align__(16) __hip_bfloat16 As[128 * 32];
    __shared__ __align__(16) __hip_bfloat16 Bs[128 * 32];
    const int t = threadIdx.x;
    const int wv = t >> 6;
    const int ln = t & 63;
    const int m16 = ln & 15, q4 = ln >> 4;
    const int row0 = blockIdx.y * 128, col0 = blockIdx.x * 128;
    const int wm = (wv >> 1) * 64, wn = (wv & 1) * 64;

    f4_t acc[4][4] = {};

    for (int k0 = 0; k0 < K; k0 += 32) {
        #pragma unroll
        for (int i = 0; i < 2; i++) {
            int s = i * 256 + t;
            int r = s >> 2, c = s & 3;
            gl_lds16(A + (size_t)(row0 + r) * K + k0 + c * 8,
                     As + (size_t)(i * 256 + wv * 64) * 8);
        }
        #pragma unroll
        for (int i = 0; i < 2; i++) {
            int s = i * 256 + t;
            int r = s >> 2, c = s & 3;
            gl_lds16(Bw + (size_t)(col0 + r) * K + k0 + c * 8,
                     Bs + (size_t)(i * 256 + wv * 64) * 8);
        }
        __syncthreads();
        bf8_t af[4], bfr[4];
        #pragma unroll
        for (int mt = 0; mt < 4; mt++)
            af[mt] = *(const bf8_t*)&As[(wm + mt * 16 + m16) * 32 + q4 * 8];
        #pragma unroll
        for (int nt = 0; nt < 4; nt++)
            bfr[nt] = *(const bf8_t*)&Bs[(wn + nt * 16 + m16) * 32 + q4 * 8];
        #pragma unroll
        for (int mt = 0; mt < 4; mt++)
            #pragma unroll
            for (int nt = 0; nt < 4; nt++)
                acc[mt][nt] = mfma16x32(af[mt], bfr[nt], acc[mt][nt]);
        __syncthreads();
    }

    #pragma unroll
    for (int nt = 0; nt < 4; nt++) {
        int cg = col0 + wn + nt * 16 + m16;
        float bv = bias[cg];
        #pragma unroll
        for (int mt = 0; mt < 4; mt++) {
            #pragma unroll
            for (int r = 0; r < 4; r++) {
                int rg = row0 + wm + mt * 16 + q4 * 4 + r;
                float v = acc[mt][nt][r] + bv;
                if constexpr (BF16_OUT)
                    ((__hip_bfloat16*)Cout)[(long)rg * ldc + cg] = __float2bfloat16(v);
                else
                    ((float*)Cout)[(long)rg * ldc + cg] = v;
            }
        }
    }
}

// ---------------- 256x256 pipelined NT GEMM for QKV (T1+T2+T3/T4+T5 stack) --------
// V-column blocks (col0 >= 2E, block-uniform) write TRANSPOSED to vt[(cg-2E)*T + rg].
// q/k-column blocks apply RoPE IN-REGISTER in the epilogue (rope_kernel deleted):
// rotate_half partner of col i is i+32 = SAME thread's acc (pairs nt={0,2},{1,3});
// cu boundaries are all multiples of 256 -> a 256-row tile never spans sequences,
// so pos0 is block-uniform. Bias folded before rotation (commutes with QSCALE).
__global__ __launch_bounds__(512, 2) void gemm256(
    const __hip_bfloat16* __restrict__ A, const __hip_bfloat16* __restrict__ Bw,
    const float* __restrict__ bias, __hip_bfloat16* __restrict__ Cout,
    __hip_bfloat16* __restrict__ vtout, int Tdim,
    const int* __restrict__ cu, int Bseq,
    int M, int N, int K, int ldc)
{
    __shared__ __align__(16) __hip_bfloat16 As[2][256 * 64];  // 2 x 32 KB
    __shared__ __align__(16) __hip_bfloat16 Bs[2][256 * 64];  // 2 x 32 KB

    const int t = threadIdx.x;
    const int wv = t >> 6, ln = t & 63;
    const int m16 = ln & 15, q4 = ln >> 4;
    const int wr = wv >> 2, wc = wv & 3;   // 2 x 4 wave grid

    const int gx = N >> 8;
    const int nwg = gridDim.x;
    const int id = blockIdx.x;
    const int swz = ((nwg & 7) == 0) ? (id & 7) * (nwg >> 3) + (id >> 3) : id;  // T1 (bijective: nwg%8==0)
    const int col0 = (swz % gx) << 8;
    const int row0 = (swz / gx) << 8;

    const int NT = K >> 6;   // K-tiles of 64

    // stage one 256x64 tile: linear LDS dest (slot order), inverse-swizzled global src
    auto stage = [&](const __hip_bfloat16* src, __hip_bfloat16* dst) {
        #pragma unroll
        for (int i = 0; i < 4; i++) {
            int s = i * 512 + t;
            int r = s >> 3, c = (s & 7) ^ (r & 7);
            gl_lds16(src + (size_t)r * K + c * 8,
                     (char*)dst + (size_t)(i * 512 + wv * 64) * 16);
        }
    };

    // prologue: tiles 0 and 1
    stage(A  + (size_t)row0 * K,      &As[0][0]);
    stage(Bw + (size_t)col0 * K,      &Bs[0][0]);
    if (NT > 1) {
        stage(A  + (size_t)row0 * K + 64, &As[1][0]);
        stage(Bw + (size_t)col0 * K + 64, &Bs[1][0]);
        asm volatile("s_waitcnt vmcnt(8)" ::: "memory");   // tile 0 landed; tile 1 in flight
    } else {
        asm volatile("s_waitcnt vmcnt(0)" ::: "memory");
    }
    __builtin_amdgcn_s_barrier();

    f4_t acc[8][4] = {};

    for (int kt = 0; kt < NT; kt++) {
        const __hip_bfloat16* Ab = &As[kt & 1][0];
        const __hip_bfloat16* Bb = &Bs[kt & 1][0];

        auto lda = [&](const __hip_bfloat16* base, int r, int kc) {
            return *(const bf8_t*)&base[r * 64 + ((((kc << 2) | q4) ^ (r & 7)) << 3)];
        };

        bf8_t afr[4][2], bf0[2][2], bf1[2][2];
        // Q(mh0,nh0): af half 0 (8 reads) + bf half 0 (4 reads)
        #pragma unroll
        for (int mt = 0; mt < 4; mt++)
            #pragma unroll
            for (int kc = 0; kc < 2; kc++)
                afr[mt][kc] = lda(Ab, wr * 128 + mt * 16 + m16, kc);
        #pragma unroll
        for (int nt = 0; nt < 2; nt++)
            #pragma unroll
            for (int kc = 0; kc < 2; kc++)
                bf0[nt][kc] = lda(Bb, wc * 64 + nt * 16 + m16, kc);

        __builtin_amdgcn_s_setprio(1);
        #pragma unroll
        for (int mt = 0; mt < 4; mt++)
            #pragma unroll
            for (int nt = 0; nt < 2; nt++)
                #pragma unroll
                for (int kc = 0; kc < 2; kc++)
                    acc[mt][nt] = mfma16x32(afr[mt][kc], bf0[nt][kc], acc[mt][nt]);
        __builtin_amdgcn_s_setprio(0);

        // Q(mh0,nh1): new bf half 1 (4 reads)
        #pragma unroll
        for (int nt = 0; nt < 2; nt++)
            #pragma unroll
            for (int kc = 0; kc < 2; kc++)
                bf1[nt][kc] = lda(Bb, wc * 64 + (2 + nt) * 16 + m16, kc);

        __builtin_amdgcn_s_setprio(1);
        #pragma unroll
        for (int mt = 0; mt < 4; mt++)
            #pragma unroll
            for (int nt = 0; nt < 2; nt++)
                #pragma unroll
                for (int kc = 0; kc < 2; kc++)
                    acc[mt][2 + nt] = mfma16x32(afr[mt][kc], bf1[nt][kc], acc[mt][2 + nt]);
        __builtin_amdgcn_s_setprio(0);

        // Q(mh1,nh1): new af half 1 (8 reads)
        #pragma unroll
        for (int mt = 0; mt < 4; mt++)
            #pragma unroll
            for (int kc = 0; kc < 2; kc++)
                afr[mt][kc] = lda(Ab, wr * 128 + (4 + mt) * 16 + m16, kc);

        __builtin_amdgcn_s_setprio(1);
        #pragma unroll
        for (int mt = 0; mt < 4; mt++)
            #pragma unroll
            for (int nt = 0; nt < 2; nt++)
                #pragma unroll
                for (int kc = 0; kc < 2; kc++)
                    acc[4 + mt][2 + nt] = mfma16x32(afr[mt][kc], bf1[nt][kc], acc[4 + mt][2 + nt]);
        __builtin_amdgcn_s_setprio(0);

        // Q(mh1,nh0): bf half 0 still live
        __builtin_amdgcn_s_setprio(1);
        #pragma unroll
        for (int mt = 0; mt < 4; mt++)
            #pragma unroll
            for (int nt = 0; nt < 2; nt++)
                #pragma unroll
                for (int kc = 0; kc < 2; kc++)
                    acc[4 + mt][nt] = mfma16x32(afr[mt][kc], bf0[nt][kc], acc[4 + mt][nt]);
        __builtin_amdgcn_s_setprio(0);

        // all reads of slot kt&1 done (per-wave lgkmcnt before MFMA; barrier -> all waves)
        asm volatile("s_waitcnt lgkmcnt(0)" ::: "memory");
        __builtin_amdgcn_s_barrier();

        if (kt + 2 < NT) {   // restage the just-freed slot for tile kt+2
            stage(A  + (size_t)row0 * K + (size_t)(kt + 2) * 64, &As[kt & 1][0]);
            stage(Bw + (size_t)col0 * K + (size_t)(kt + 2) * 64, &Bs[kt & 1][0]);
        }
        if (kt + 1 < NT) {
            if (kt + 2 < NT)
                asm volatile("s_waitcnt vmcnt(8)" ::: "memory");  // tile kt+1 landed; kt+2 in flight
            else
                asm volatile("s_waitcnt vmcnt(0)" ::: "memory");  // drain last tile
            __builtin_amdgcn_s_barrier();
        }
    }

    if (col0 >= 2 * E_DIM) {
        // V block: write transposed into vt, 8B bf4 per (mt,nt) (4 consecutive tokens)
        #pragma unroll
        for (int nt = 0; nt < 4; nt++) {
            int cg = col0 + wc * 64 + nt * 16 + m16;
            float bval = bias[cg];
            int vrow = cg - 2 * E_DIM;
            #pragma unroll
            for (int mt = 0; mt < 8; mt++) {
                int rg0 = row0 + wr * 128 + mt * 16 + q4 * 4;
                f4_t vv;
                #pragma unroll
                for (int r = 0; r < 4; r++) vv[r] = acc[mt][nt][r] + bval;
                *(bf4_t*)&vtout[(long)vrow * Tdim + rg0] = pk4(vv);
            }
        }
    } else {
        // q/k block: fused RoPE. Block-uniform seq start (cu all multiples of 256).
        int seqs = 0;
        for (int b = 0; b < Bseq; ++b) { int c0 = cu[b]; if (c0 <= row0) seqs = c0; }
        const int pos0 = row0 - seqs + wr * 128 + q4 * 4;
        float bval[4];
        #pragma unroll
        for (int nt = 0; nt < 4; nt++) bval[nt] = bias[col0 + wc * 64 + nt * 16 + m16];
        #pragma unroll
        for (int p = 0; p < 2; p++) {   // pair (nt=p, nt=p+2): i = p*16+m16, partner i+32
            float invf = exp2f(-(float)(p * 16 + m16) * 0.41524100558003436f);
            #pragma unroll
            for (int mt = 0; mt < 8; mt++) {
                #pragma unroll
                for (int r = 0; r < 4; r++) {
                    float f = (float)(pos0 + mt * 16 + r) * invf;
                    float sn, cs;
                    sincosf(f, &sn, &cs);
                    float a  = acc[mt][p][r]     + bval[p];
                    float b2 = acc[mt][p + 2][r] + bval[p + 2];
                    acc[mt][p][r]     = a * cs - b2 * sn;
                    acc[mt][p + 2][r] = b2 * cs + a * sn;
                }
            }
        }
        #pragma unroll
        for (int nt = 0; nt < 4; nt++) {
            int cg = col0 + wc * 64 + nt * 16 + m16;
            #pragma unroll
            for (int mt = 0; mt < 8; mt++) {
                #pragma unroll
                for (int r = 0; r < 4; r++) {
                    int rg = row0 + wr * 128 + mt * 16 + q4 * 4 + r;
                    Cout[(long)rg * ldc + cg] = __float2bfloat16(acc[mt][nt][r]);
                }
            }
        }
    }
}

// ---------------- flash attention: round-7 structure (KVBLK=64, 2-phase, 4 blk/CU,
// longest-first). Byte-identical to the round-7 kernel for clean attribution. ----
__global__ __launch_bounds__(256, 4) void attn_kernel(
    const __hip_bfloat16* __restrict__ qkv, const __hip_bfloat16* __restrict__ vt,
    const int* __restrict__ cu, __hip_bfloat16* __restrict__ obuf, int B, int T)
{
    __shared__ __align__(16) __hip_bfloat16 Ks[2][64 * 64];  // [key][d] swizzled, 2x8 KB
    __shared__ __align__(16) __hip_bfloat16 Vs[2][64 * 64];  // [d][key] swizzled, 2x8 KB

    int idx = blockIdx.x;
    int h = idx % NHEADS;
    int gt = idx / NHEADS;
    // longest-first: sequences sorted ascending in cu -> scan in REVERSE
    int b = B - 1, l = 0, seq0 = 0;
    for (; b >= 0; --b) {
        seq0 = cu[b];
        l = cu[b + 1] - seq0;
        int ntile = (l + 127) >> 7;
        if (gt < ntile) break;
        gt -= ntile;
    }
    if (b < 0) return;
    int q0 = gt * 128;
    const int NT = (l + 63) >> 6;

    const int t = threadIdx.x;
    const int wv = t >> 6, ln = t & 63;
    const int m16 = ln & 15, q4 = ln >> 4;

    // K: slot s2 -> key s2>>3, chunk (s2&7)^(key&7); V: d s2>>3, chunk (s2&7)^(d&7)
    auto stage_full = [&](int kv0n, int bi) {
        #pragma unroll
        for (int i = 0; i < 2; i++) {
            int s2 = i * 256 + t;
            int key = s2 >> 3, cg = (s2 & 7) ^ (key & 7);
            gl_lds16(qkv + (long)(seq0 + kv0n + key) * QKV_LD + E_DIM + h * HDIM + cg * 8,
                     (char*)&Ks[bi][0] + (size_t)(i * 256 + wv * 64) * 16);
        }
        #pragma unroll
        for (int i = 0; i < 2; i++) {
            int s2 = i * 256 + t;
            int d = s2 >> 3, cg = (s2 & 7) ^ (d & 7);
            gl_lds16(vt + (long)(h * HDIM + d) * T + seq0 + kv0n + cg * 8,
                     (char*)&Vs[bi][0] + (size_t)(i * 256 + wv * 64) * 16);
        }
    };
    auto stage_tail = [&](int kv0n, int bi) {   // dead in this workload (l % 128 == 0)
        #pragma unroll
        for (int i = 0; i < 2; i++) {
            int s2 = i * 256 + t;
            int key = s2 >> 3, c = s2 & 7;
            bf8_t v = (bf8_t)0;
            if (kv0n + key < l)
                v = *(const bf8_t*)(qkv + (long)(seq0 + kv0n + key) * QKV_LD + E_DIM + h * HDIM + c * 8);
            *(bf8_t*)&Ks[bi][key * 64 + (c ^ (key & 7)) * 8] = v;
        }
        #pragma unroll
        for (int i = 0; i < 2; i++) {
            int s2 = i * 256 + t;
            int d = s2 >> 3, c = s2 & 7;
            bf8_t v = (bf8_t)0;
            int tb = kv0n + c * 8;
            #pragma unroll
            for (int u = 0; u < 8; u++)
                if (tb + u < l)
                    v[u] = *(const short*)&vt[(long)(h * HDIM + d) * T + seq0 + tb + u];
            *(bf8_t*)&Vs[bi][d * 64 + (c ^ (d & 7)) * 8] = v;
        }
    };

    // prologue: issue staging of tile 0 first, then load Q while it flies
    if (64 <= l) stage_full(0, 0); else stage_tail(0, 0);

    // Q B-frags in registers: bq[nt][kc] = B[k=kc*32+q4*8+j][n=m16]
    bf8_t bq[2][2];
    #pragma unroll
    for (int nt = 0; nt < 2; nt++) {
        int qrow = q0 + wv * 32 + nt * 16 + m16;
        #pragma unroll
        for (int kc = 0; kc < 2; kc++) {
            bf8_t v = (bf8_t)0;
            if (qrow < l)
                v = *(const bf8_t*)(qkv + (long)(seq0 + qrow) * QKV_LD + h * HDIM + kc * 32 + q4 * 8);
            bq[nt][kc] = v;
        }
    }

    f4_t oacc[2][4] = {};
    float m_s[2] = {-1e30f, -1e30f};
    float l_s[2] = {0.0f, 0.0f};

    const int ksw0 = (q4 ^ (m16 & 7)) * 8;        // slot of global chunk q4
    const int ksw1 = ((4 + q4) ^ (m16 & 7)) * 8;  // slot of global chunk 4+q4

    asm volatile("s_waitcnt vmcnt(0) lgkmcnt(0)" ::: "memory");
    __builtin_amdgcn_s_barrier();

    for (int it = 0; it < NT; ++it) {
        const int kv0 = it << 6;
        const bool full = (kv0 + 64 <= l);
        if (it + 1 < NT) {                       // issue next tile's loads NOW
            int kvn = kv0 + 64;
            if (kvn + 64 <= l) stage_full(kvn, (it + 1) & 1);
            else stage_tail(kvn, (it + 1) & 1);
        }
        const __hip_bfloat16* Kb = Ks[it & 1];
        const __hip_bfloat16* Vb = Vs[it & 1];

        // S^T = K.Q^T : S[nt][mt] holds S^T[key=mt*16+q4*4+r][qrow=m16]
        f4_t S[2][4];
        __builtin_amdgcn_s_setprio(1);
        #pragma unroll
        for (int mt = 0; mt < 4; mt++) {
            const __hip_bfloat16* krow = &Kb[(mt * 16 + m16) * 64];
            bf8_t ak0 = *(const bf8_t*)(krow + ksw0);
            bf8_t ak1 = *(const bf8_t*)(krow + ksw1);
            #pragma unroll
            for (int nt = 0; nt < 2; nt++) {
                f4_t a = {};
                a = mfma16x32(ak0, bq[nt][0], a);
                a = mfma16x32(ak1, bq[nt][1], a);
                S[nt][mt] = a;
            }
        }
        __builtin_amdgcn_s_setprio(0);

        if (!full) {
            #pragma unroll
            for (int mt = 0; mt < 4; mt++) {
                #pragma unroll
                for (int r = 0; r < 4; r++) {
                    bool valid = (kv0 + mt * 16 + q4 * 4 + r) < l;
                    #pragma unroll
                    for (int nt = 0; nt < 2; nt++)
                        if (!valid) S[nt][mt][r] = -1e30f;
                }
            }
        }

        // online softmax (base-2 domain; log2e folded into Wq/bq) + defer-max (THR=8)
        // tree reductions: fmax depth 4, ls partials depth ~6
        #pragma unroll
        for (int nt = 0; nt < 2; nt++) {
            float pm[4];
            #pragma unroll
            for (int mt = 0; mt < 4; mt++)
                pm[mt] = fmaxf(fmaxf(S[nt][mt][0], S[nt][mt][1]),
                               fmaxf(S[nt][mt][2], S[nt][mt][3]));
            float mx = fmaxf(fmaxf(pm[0], pm[1]), fmaxf(pm[2], pm[3]));
            mx = fmaxf(mx, __shfl_xor(mx, 16));
            mx = fmaxf(mx, __shfl_xor(mx, 32));
            if (!__all(mx - m_s[nt] <= 8.0f)) {
                float mn = fmaxf(m_s[nt], mx);
                float al = exp2f(m_s[nt] - mn);
                m_s[nt] = mn;
                l_s[nt] *= al;
                #pragma unroll
                for (int dt = 0; dt < 4; dt++)
                    #pragma unroll
                    for (int r = 0; r < 4; r++)
                        oacc[nt][dt][r] *= al;
            }
            float mcur = m_s[nt];
            float ps[4];
            #pragma unroll
            for (int mt = 0; mt < 4; mt++) {
                f4_t p;
                p[0] = exp2f(S[nt][mt][0] - mcur);
                p[1] = exp2f(S[nt][mt][1] - mcur);
                p[2] = exp2f(S[nt][mt][2] - mcur);
                p[3] = exp2f(S[nt][mt][3] - mcur);
                S[nt][mt] = p;
                ps[mt] = (p[0] + p[1]) + (p[2] + p[3]);
            }
            l_s[nt] += (ps[0] + ps[1]) + (ps[2] + ps[3]);
        }

        // O^T += V^T . P^T  (A=V^T from swizzled LDS, B=P^T packed in-place)
        __builtin_amdgcn_s_setprio(1);
        #pragma unroll
        for (int mt = 0; mt < 4; mt++) {
            bf4_t bp0 = pk4(S[0][mt]);
            bf4_t bp1 = pk4(S[1][mt]);
            const int vsw = ((mt * 2 + (q4 >> 1)) ^ (m16 & 7)) * 8 + (q4 & 1) * 4;
            #pragma unroll
            for (int dt = 0; dt < 4; dt++) {
                bf4_t av = *(const bf4_t*)&Vb[(dt * 16 + m16) * 64 + vsw];
                oacc[0][dt] = mfma16x16(av, bp0, oacc[0][dt]);
                oacc[1][dt] = mfma16x16(av, bp1, oacc[1][dt]);
            }
        }
        __builtin_amdgcn_s_setprio(0);

        if (it + 1 < NT) {
            // wait for next tile's staging (issued before compute -> mostly landed)
            // and make all waves' LDS writes visible; ONE barrier per tile.
            asm volatile("s_waitcnt vmcnt(0) lgkmcnt(0)" ::: "memory");
            __builtin_amdgcn_s_barrier();
        }
    }

    // finalize
    #pragma unroll
    for (int nt = 0; nt < 2; nt++) {
        float ls = l_s[nt];
        ls += __shfl_xor(ls, 16);
        ls += __shfl_xor(ls, 32);
        float inv = 1.0f / ls;
        int qrow = q0 + wv * 32 + nt * 16 + m16;
        if (qrow < l) {
            #pragma unroll
            for (int dt = 0; dt < 4; dt++) {
                f4_t o;
                #pragma unroll
                for (int r = 0; r < 4; r++)
                    o[r] = oacc[nt][dt][r] * inv;
                *(bf4_t*)&obuf[(long)(seq0 + qrow) * E_DIM + h * HDIM + dt * 16 + q4 * 4] = pk4(o);
            }
        }
    }
}

// ---------------- launch ----------------
extern "C" void kernel_launch(void* const* d_in, const int* in_sizes, int n_in,
                              void* d_out, int out_size, void* d_ws, size_t ws_size,
                              hipStream_t stream) {
    const int E = E_DIM;
    const int T = in_sizes[0] / E;      // 8192
    const int B = in_sizes[1] - 1;      // 8

    const float* x  = (const float*)d_in[0];
    const int*   cu = (const int*)d_in[1];
    const float* Wq = (const float*)d_in[3];
    const float* bq = (const float*)d_in[4];
    const float* Wk = (const float*)d_in[5];
    const float* bk = (const float*)d_in[6];
    const float* Wv = (const float*)d_in[7];
    const float* bv = (const float*)d_in[8];
    const float* Wo = (const float*)d_in[9];
    const float* bo = (const float*)d_in[10];

    char* ws = (char*)d_ws;
    size_t off = 0;
    auto alloc = [&](size_t bytes) -> void* {
        void* p = ws + off;
        off = (off + bytes + 255) & ~(size_t)255;
        return p;
    };
    __hip_bfloat16* xbf   = (__hip_bfloat16*)alloc((size_t)T * E * 2);
    __hip_bfloat16* wqkv  = (__hip_bfloat16*)alloc((size_t)3 * E * E * 2);
    __hip_bfloat16* wobf  = (__hip_bfloat16*)alloc((size_t)E * E * 2);
    float*          bqkv  = (float*)alloc((size_t)3 * E * 4);
    __hip_bfloat16* qkvb  = (__hip_bfloat16*)alloc((size_t)T * 3 * E * 2);
    __hip_bfloat16* vt    = (__hip_bfloat16*)alloc((size_t)E * T * 2);
    __hip_bfloat16* obuf  = xbf;  // alias: x_bf dead after QKV GEMM

    long nx8 = (long)T * E / 8;
    long nw8 = (long)E * E / 8;
    long nb8 = (long)3 * E / 8;
    long total = nx8 + 4 * nw8 + nb8;
    int pblocks = (int)((total + 255) / 256);
    prep_kernel<<<pblocks, 256, 0, stream>>>(x, Wq, Wk, Wv, Wo, bq, bk, bv,
                                             xbf, wqkv, wobf, bqkv, nx8, nw8, nb8);

    // QKV projection: 256^2-tile pipelined GEMM; RoPE fused into q/k epilogue,
    // V columns written transposed to vt. rope_kernel deleted.
    gemm256<<<(T / 256) * (3 * E / 256), 512, 0, stream>>>(
        xbf, wqkv, bqkv, qkvb, vt, T, cu, B, T, 3 * E, E, 3 * E);

    // 128-row q-tiles: upper bound on sum of per-seq ceil(l/128)
    int qtiles_ub = T / 128 + B;
    attn_kernel<<<qtiles_ub * NHEADS, 256, 0, stream>>>(qkvb, vt, cu, obuf, B, T);

    // output projection: N=1280 -> only 160 blocks at 256^2; keep 128^2 (640 blocks)
    gemm_nt<false><<<dim3(E / 128, T / 128), 256, 0, stream>>>(
        obuf, wobf, bo, d_out, T, E, E, E);
}

// Round 9
// 387.210 us; speedup vs baseline: 1.1363x; 1.1363x over previous
//
#include <hip/hip_runtime.h>
#include <hip/hip_bf16.h>
#include <cstdint>

#define E_DIM   1280
#define NHEADS  20
#define HDIM    64
#define QKV_LD  3840   // 3*E

typedef __attribute__((ext_vector_type(8))) short bf8_t;   // 8 bf16 (4 VGPRs)
typedef __attribute__((ext_vector_type(4))) short bf4_t;   // 4 bf16 (2 VGPRs)
typedef __attribute__((ext_vector_type(4))) float f4_t;    // MFMA accumulator

__device__ __forceinline__ short f2bs(float f) {
    union { __hip_bfloat16 h; short s; } u;
    u.h = __float2bfloat16(f);
    return u.s;
}

// hardware packed f32x2 -> bf16x2 (RNE), T12 recipe: no builtin on gfx950
__device__ __forceinline__ bf4_t pk4(f4_t s) {
    union { bf4_t v; uint32_t u[2]; } r;
    asm("v_cvt_pk_bf16_f32 %0, %1, %2" : "=v"(r.u[0]) : "v"(s[0]), "v"(s[1]));
    asm("v_cvt_pk_bf16_f32 %0, %1, %2" : "=v"(r.u[1]) : "v"(s[2]), "v"(s[3]));
    return r.v;
}

__device__ __forceinline__ f4_t mfma16x32(bf8_t a, bf8_t b, f4_t c) {
    return __builtin_amdgcn_mfma_f32_16x16x32_bf16(a, b, c, 0, 0, 0);
}
__device__ __forceinline__ f4_t mfma16x16(bf4_t a, bf4_t b, f4_t c) {
    return __builtin_amdgcn_mfma_f32_16x16x16bf16_1k(a, b, c, 0, 0, 0);
}

// async global->LDS, 16B per lane. LDS dest is wave-uniform base + lane*16.
__device__ __forceinline__ void gl_lds16(const void* g, void* l) {
    auto gp = reinterpret_cast<__attribute__((address_space(1))) unsigned int*>(
        reinterpret_cast<uintptr_t>(g));
    auto lp = reinterpret_cast<__attribute__((address_space(3))) unsigned int*>(
        reinterpret_cast<uintptr_t>(l));
    __builtin_amdgcn_global_load_lds(gp, lp, 16, 0, 0);
}

// ---------------- prep: casts + weight concat + bias concat ----------------
// Wq/bq scale = d^-0.5 * log2(e): softmax computed in base-2 domain (exp2f).
#define QSCALE 0.18033688011112042f

__device__ __forceinline__ void cvt8(__hip_bfloat16* dst, const float* src, float sc) {
    float4 a = *(const float4*)src;
    float4 b = *(const float4*)(src + 4);
    bf8_t v;
    v[0] = f2bs(a.x * sc); v[1] = f2bs(a.y * sc); v[2] = f2bs(a.z * sc); v[3] = f2bs(a.w * sc);
    v[4] = f2bs(b.x * sc); v[5] = f2bs(b.y * sc); v[6] = f2bs(b.z * sc); v[7] = f2bs(b.w * sc);
    *(bf8_t*)dst = v;
}

__global__ __launch_bounds__(256) void prep_kernel(
    const float* __restrict__ x,
    const float* __restrict__ wq, const float* __restrict__ wk,
    const float* __restrict__ wv, const float* __restrict__ wo,
    const float* __restrict__ bq, const float* __restrict__ bk, const float* __restrict__ bv,
    __hip_bfloat16* __restrict__ xbf, __hip_bfloat16* __restrict__ wqkv,
    __hip_bfloat16* __restrict__ wobf, float* __restrict__ bqkv,
    long nx8, long nw8, long nb8)
{
    long u = (long)blockIdx.x * 256 + threadIdx.x;
    if (u < nx8) { cvt8(xbf + u * 8, x + u * 8, 1.0f); return; }
    u -= nx8;
    if (u < 3 * nw8) {
        long e = u * 8;
        long w1 = nw8 * 8;
        const float* src; float sc;
        if (e < w1)            { src = wq + e;           sc = QSCALE; }
        else if (e < 2 * w1)   { src = wk + (e - w1);    sc = 1.0f; }
        else                   { src = wv + (e - 2*w1);  sc = 1.0f; }
        cvt8(wqkv + e, src, sc);
        return;
    }
    u -= 3 * nw8;
    if (u < nw8) { cvt8(wobf + u * 8, wo + u * 8, 1.0f); return; }
    u -= nw8;
    if (u < nb8) {
        long e = u * 8;
        #pragma unroll
        for (int j = 0; j < 8; j++) {
            long i = e + j;
            float v;
            if (i < E_DIM)           v = bq[i] * QSCALE;
            else if (i < 2 * E_DIM)  v = bk[i - E_DIM];
            else                     v = bv[i - 2 * E_DIM];
            bqkv[i] = v;
        }
    }
}

// ---------------- m97-style NT GEMM (output proj): C = A*B^T + bias ----------------
template<bool BF16_OUT>
__global__ __launch_bounds__(256, 3) void gemm_nt(
    const __hip_bfloat16* __restrict__ A, const __hip_bfloat16* __restrict__ Bw,
    const float* __restrict__ bias, void* __restrict__ Cout,
    int M, int N, int K, int ldc)
{
    __shared__ __align__(16) __hip_bfloat16 As[128 * 32];
    __shared__ __align__(16) __hip_bfloat16 Bs[128 * 32];
    const int t = threadIdx.x;
    const int wv = t >> 6;
    const int ln = t & 63;
    const int m16 = ln & 15, q4 = ln >> 4;
    const int row0 = blockIdx.y * 128, col0 = blockIdx.x * 128;
    const int wm = (wv >> 1) * 64, wn = (wv & 1) * 64;

    f4_t acc[4][4] = {};

    for (int k0 = 0; k0 < K; k0 += 32) {
        #pragma unroll
        for (int i = 0; i < 2; i++) {
            int s = i * 256 + t;
            int r = s >> 2, c = s & 3;
            gl_lds16(A + (size_t)(row0 + r) * K + k0 + c * 8,
                     As + (size_t)(i * 256 + wv * 64) * 8);
        }
        #pragma unroll
        for (int i = 0; i < 2; i++) {
            int s = i * 256 + t;
            int r = s >> 2, c = s & 3;
            gl_lds16(Bw + (size_t)(col0 + r) * K + k0 + c * 8,
                     Bs + (size_t)(i * 256 + wv * 64) * 8);
        }
        __syncthreads();
        bf8_t af[4], bfr[4];
        #pragma unroll
        for (int mt = 0; mt < 4; mt++)
            af[mt] = *(const bf8_t*)&As[(wm + mt * 16 + m16) * 32 + q4 * 8];
        #pragma unroll
        for (int nt = 0; nt < 4; nt++)
            bfr[nt] = *(const bf8_t*)&Bs[(wn + nt * 16 + m16) * 32 + q4 * 8];
        #pragma unroll
        for (int mt = 0; mt < 4; mt++)
            #pragma unroll
            for (int nt = 0; nt < 4; nt++)
                acc[mt][nt] = mfma16x32(af[mt], bfr[nt], acc[mt][nt]);
        __syncthreads();
    }

    #pragma unroll
    for (int nt = 0; nt < 4; nt++) {
        int cg = col0 + wn + nt * 16 + m16;
        float bv = bias[cg];
        #pragma unroll
        for (int mt = 0; mt < 4; mt++) {
            #pragma unroll
            for (int r = 0; r < 4; r++) {
                int rg = row0 + wm + mt * 16 + q4 * 4 + r;
                float v = acc[mt][nt][r] + bv;
                if constexpr (BF16_OUT)
                    ((__hip_bfloat16*)Cout)[(long)rg * ldc + cg] = __float2bfloat16(v);
                else
                    ((float*)Cout)[(long)rg * ldc + cg] = v;
            }
        }
    }
}

// ---------------- 256x256 pipelined NT GEMM for QKV (T1+T2+T3/T4+T5 stack) --------
// V-column blocks (col0 >= 2E, block-uniform) write TRANSPOSED to vt[(cg-2E)*T + rg].
// q/k-column blocks apply RoPE IN-REGISTER in the epilogue. Round-8 lesson: sincosf's
// accurate libm path (Payne-Hanek for angles up to 1279 rad) allocates SCRATCH arrays
// -> +320 MB phantom write traffic, gemm256 110->193us. Fix: hardware v_sin_f32 /
// v_cos_f32 (input in REVOLUTIONS, fract range-reduction, zero scratch). 1/(2pi) is
// folded into the per-column frequency: invf_rev = exp2(-i*0.41524 - log2(2pi)).
__global__ __launch_bounds__(512, 2) void gemm256(
    const __hip_bfloat16* __restrict__ A, const __hip_bfloat16* __restrict__ Bw,
    const float* __restrict__ bias, __hip_bfloat16* __restrict__ Cout,
    __hip_bfloat16* __restrict__ vtout, int Tdim,
    const int* __restrict__ cu, int Bseq,
    int M, int N, int K, int ldc)
{
    __shared__ __align__(16) __hip_bfloat16 As[2][256 * 64];  // 2 x 32 KB
    __shared__ __align__(16) __hip_bfloat16 Bs[2][256 * 64];  // 2 x 32 KB

    const int t = threadIdx.x;
    const int wv = t >> 6, ln = t & 63;
    const int m16 = ln & 15, q4 = ln >> 4;
    const int wr = wv >> 2, wc = wv & 3;   // 2 x 4 wave grid

    const int gx = N >> 8;
    const int nwg = gridDim.x;
    const int id = blockIdx.x;
    const int swz = ((nwg & 7) == 0) ? (id & 7) * (nwg >> 3) + (id >> 3) : id;  // T1 (bijective: nwg%8==0)
    const int col0 = (swz % gx) << 8;
    const int row0 = (swz / gx) << 8;

    const int NT = K >> 6;   // K-tiles of 64

    // stage one 256x64 tile: linear LDS dest (slot order), inverse-swizzled global src
    auto stage = [&](const __hip_bfloat16* src, __hip_bfloat16* dst) {
        #pragma unroll
        for (int i = 0; i < 4; i++) {
            int s = i * 512 + t;
            int r = s >> 3, c = (s & 7) ^ (r & 7);
            gl_lds16(src + (size_t)r * K + c * 8,
                     (char*)dst + (size_t)(i * 512 + wv * 64) * 16);
        }
    };

    // prologue: tiles 0 and 1
    stage(A  + (size_t)row0 * K,      &As[0][0]);
    stage(Bw + (size_t)col0 * K,      &Bs[0][0]);
    if (NT > 1) {
        stage(A  + (size_t)row0 * K + 64, &As[1][0]);
        stage(Bw + (size_t)col0 * K + 64, &Bs[1][0]);
        asm volatile("s_waitcnt vmcnt(8)" ::: "memory");   // tile 0 landed; tile 1 in flight
    } else {
        asm volatile("s_waitcnt vmcnt(0)" ::: "memory");
    }
    __builtin_amdgcn_s_barrier();

    f4_t acc[8][4] = {};

    for (int kt = 0; kt < NT; kt++) {
        const __hip_bfloat16* Ab = &As[kt & 1][0];
        const __hip_bfloat16* Bb = &Bs[kt & 1][0];

        auto lda = [&](const __hip_bfloat16* base, int r, int kc) {
            return *(const bf8_t*)&base[r * 64 + ((((kc << 2) | q4) ^ (r & 7)) << 3)];
        };

        bf8_t afr[4][2], bf0[2][2], bf1[2][2];
        // Q(mh0,nh0): af half 0 (8 reads) + bf half 0 (4 reads)
        #pragma unroll
        for (int mt = 0; mt < 4; mt++)
            #pragma unroll
            for (int kc = 0; kc < 2; kc++)
                afr[mt][kc] = lda(Ab, wr * 128 + mt * 16 + m16, kc);
        #pragma unroll
        for (int nt = 0; nt < 2; nt++)
            #pragma unroll
            for (int kc = 0; kc < 2; kc++)
                bf0[nt][kc] = lda(Bb, wc * 64 + nt * 16 + m16, kc);

        __builtin_amdgcn_s_setprio(1);
        #pragma unroll
        for (int mt = 0; mt < 4; mt++)
            #pragma unroll
            for (int nt = 0; nt < 2; nt++)
                #pragma unroll
                for (int kc = 0; kc < 2; kc++)
                    acc[mt][nt] = mfma16x32(afr[mt][kc], bf0[nt][kc], acc[mt][nt]);
        __builtin_amdgcn_s_setprio(0);

        // Q(mh0,nh1): new bf half 1 (4 reads)
        #pragma unroll
        for (int nt = 0; nt < 2; nt++)
            #pragma unroll
            for (int kc = 0; kc < 2; kc++)
                bf1[nt][kc] = lda(Bb, wc * 64 + (2 + nt) * 16 + m16, kc);

        __builtin_amdgcn_s_setprio(1);
        #pragma unroll
        for (int mt = 0; mt < 4; mt++)
            #pragma unroll
            for (int nt = 0; nt < 2; nt++)
                #pragma unroll
                for (int kc = 0; kc < 2; kc++)
                    acc[mt][2 + nt] = mfma16x32(afr[mt][kc], bf1[nt][kc], acc[mt][2 + nt]);
        __builtin_amdgcn_s_setprio(0);

        // Q(mh1,nh1): new af half 1 (8 reads)
        #pragma unroll
        for (int mt = 0; mt < 4; mt++)
            #pragma unroll
            for (int kc = 0; kc < 2; kc++)
                afr[mt][kc] = lda(Ab, wr * 128 + (4 + mt) * 16 + m16, kc);

        __builtin_amdgcn_s_setprio(1);
        #pragma unroll
        for (int mt = 0; mt < 4; mt++)
            #pragma unroll
            for (int nt = 0; nt < 2; nt++)
                #pragma unroll
                for (int kc = 0; kc < 2; kc++)
                    acc[4 + mt][2 + nt] = mfma16x32(afr[mt][kc], bf1[nt][kc], acc[4 + mt][2 + nt]);
        __builtin_amdgcn_s_setprio(0);

        // Q(mh1,nh0): bf half 0 still live
        __builtin_amdgcn_s_setprio(1);
        #pragma unroll
        for (int mt = 0; mt < 4; mt++)
            #pragma unroll
            for (int nt = 0; nt < 2; nt++)
                #pragma unroll
                for (int kc = 0; kc < 2; kc++)
                    acc[4 + mt][nt] = mfma16x32(afr[mt][kc], bf0[nt][kc], acc[4 + mt][nt]);
        __builtin_amdgcn_s_setprio(0);

        // all reads of slot kt&1 done (per-wave lgkmcnt before MFMA; barrier -> all waves)
        asm volatile("s_waitcnt lgkmcnt(0)" ::: "memory");
        __builtin_amdgcn_s_barrier();

        if (kt + 2 < NT) {   // restage the just-freed slot for tile kt+2
            stage(A  + (size_t)row0 * K + (size_t)(kt + 2) * 64, &As[kt & 1][0]);
            stage(Bw + (size_t)col0 * K + (size_t)(kt + 2) * 64, &Bs[kt & 1][0]);
        }
        if (kt + 1 < NT) {
            if (kt + 2 < NT)
                asm volatile("s_waitcnt vmcnt(8)" ::: "memory");  // tile kt+1 landed; kt+2 in flight
            else
                asm volatile("s_waitcnt vmcnt(0)" ::: "memory");  // drain last tile
            __builtin_amdgcn_s_barrier();
        }
    }

    if (col0 >= 2 * E_DIM) {
        // V block: write transposed into vt, 8B bf4 per (mt,nt) (4 consecutive tokens)
        #pragma unroll
        for (int nt = 0; nt < 4; nt++) {
            int cg = col0 + wc * 64 + nt * 16 + m16;
            float bval = bias[cg];
            int vrow = cg - 2 * E_DIM;
            #pragma unroll
            for (int mt = 0; mt < 8; mt++) {
                int rg0 = row0 + wr * 128 + mt * 16 + q4 * 4;
                f4_t vv;
                #pragma unroll
                for (int r = 0; r < 4; r++) vv[r] = acc[mt][nt][r] + bval;
                *(bf4_t*)&vtout[(long)vrow * Tdim + rg0] = pk4(vv);
            }
        }
    } else {
        // q/k block: fused RoPE via HW v_sin/v_cos (revolutions domain, no scratch).
        // Block-uniform seq start (cu all multiples of 256).
        int seqs = 0;
        for (int b = 0; b < Bseq; ++b) { int c0 = cu[b]; if (c0 <= row0) seqs = c0; }
        const int pos0 = row0 - seqs + wr * 128 + q4 * 4;
        float bval[4];
        #pragma unroll
        for (int nt = 0; nt < 4; nt++) bval[nt] = bias[col0 + wc * 64 + nt * 16 + m16];
        #pragma unroll
        for (int p = 0; p < 2; p++) {   // pair (nt=p, nt=p+2): i = p*16+m16, partner i+32
            // revolutions per position: exp2(-i*log2(10000)/32 - log2(2*pi))
            float invf = exp2f(-(float)(p * 16 + m16) * 0.41524100558003436f
                               - 2.6514961294723187f);
            #pragma unroll
            for (int mt = 0; mt < 8; mt++) {
                #pragma unroll
                for (int r = 0; r < 4; r++) {
                    float rev = (float)(pos0 + mt * 16 + r) * invf;
                    rev = rev - floorf(rev);          // range-reduce to [0,1)
                    float sn, cs;
                    asm("v_sin_f32 %0, %1" : "=v"(sn) : "v"(rev));
                    asm("v_cos_f32 %0, %1" : "=v"(cs) : "v"(rev));
                    float a  = acc[mt][p][r]     + bval[p];
                    float b2 = acc[mt][p + 2][r] + bval[p + 2];
                    acc[mt][p][r]     = a * cs - b2 * sn;
                    acc[mt][p + 2][r] = b2 * cs + a * sn;
                }
            }
        }
        #pragma unroll
        for (int nt = 0; nt < 4; nt++) {
            int cg = col0 + wc * 64 + nt * 16 + m16;
            #pragma unroll
            for (int mt = 0; mt < 8; mt++) {
                #pragma unroll
                for (int r = 0; r < 4; r++) {
                    int rg = row0 + wr * 128 + mt * 16 + q4 * 4 + r;
                    Cout[(long)rg * ldc + cg] = __float2bfloat16(acc[mt][nt][r]);
                }
            }
        }
    }
}

// ---------------- flash attention: round-7 structure (KVBLK=64, 2-phase, 4 blk/CU,
// longest-first). Byte-identical to the round-7 kernel for clean attribution. ----
__global__ __launch_bounds__(256, 4) void attn_kernel(
    const __hip_bfloat16* __restrict__ qkv, const __hip_bfloat16* __restrict__ vt,
    const int* __restrict__ cu, __hip_bfloat16* __restrict__ obuf, int B, int T)
{
    __shared__ __align__(16) __hip_bfloat16 Ks[2][64 * 64];  // [key][d] swizzled, 2x8 KB
    __shared__ __align__(16) __hip_bfloat16 Vs[2][64 * 64];  // [d][key] swizzled, 2x8 KB

    int idx = blockIdx.x;
    int h = idx % NHEADS;
    int gt = idx / NHEADS;
    // longest-first: sequences sorted ascending in cu -> scan in REVERSE
    int b = B - 1, l = 0, seq0 = 0;
    for (; b >= 0; --b) {
        seq0 = cu[b];
        l = cu[b + 1] - seq0;
        int ntile = (l + 127) >> 7;
        if (gt < ntile) break;
        gt -= ntile;
    }
    if (b < 0) return;
    int q0 = gt * 128;
    const int NT = (l + 63) >> 6;

    const int t = threadIdx.x;
    const int wv = t >> 6, ln = t & 63;
    const int m16 = ln & 15, q4 = ln >> 4;

    // K: slot s2 -> key s2>>3, chunk (s2&7)^(key&7); V: d s2>>3, chunk (s2&7)^(d&7)
    auto stage_full = [&](int kv0n, int bi) {
        #pragma unroll
        for (int i = 0; i < 2; i++) {
            int s2 = i * 256 + t;
            int key = s2 >> 3, cg = (s2 & 7) ^ (key & 7);
            gl_lds16(qkv + (long)(seq0 + kv0n + key) * QKV_LD + E_DIM + h * HDIM + cg * 8,
                     (char*)&Ks[bi][0] + (size_t)(i * 256 + wv * 64) * 16);
        }
        #pragma unroll
        for (int i = 0; i < 2; i++) {
            int s2 = i * 256 + t;
            int d = s2 >> 3, cg = (s2 & 7) ^ (d & 7);
            gl_lds16(vt + (long)(h * HDIM + d) * T + seq0 + kv0n + cg * 8,
                     (char*)&Vs[bi][0] + (size_t)(i * 256 + wv * 64) * 16);
        }
    };
    auto stage_tail = [&](int kv0n, int bi) {   // dead in this workload (l % 128 == 0)
        #pragma unroll
        for (int i = 0; i < 2; i++) {
            int s2 = i * 256 + t;
            int key = s2 >> 3, c = s2 & 7;
            bf8_t v = (bf8_t)0;
            if (kv0n + key < l)
                v = *(const bf8_t*)(qkv + (long)(seq0 + kv0n + key) * QKV_LD + E_DIM + h * HDIM + c * 8);
            *(bf8_t*)&Ks[bi][key * 64 + (c ^ (key & 7)) * 8] = v;
        }
        #pragma unroll
        for (int i = 0; i < 2; i++) {
            int s2 = i * 256 + t;
            int d = s2 >> 3, c = s2 & 7;
            bf8_t v = (bf8_t)0;
            int tb = kv0n + c * 8;
            #pragma unroll
            for (int u = 0; u < 8; u++)
                if (tb + u < l)
                    v[u] = *(const short*)&vt[(long)(h * HDIM + d) * T + seq0 + tb + u];
            *(bf8_t*)&Vs[bi][d * 64 + (c ^ (d & 7)) * 8] = v;
        }
    };

    // prologue: issue staging of tile 0 first, then load Q while it flies
    if (64 <= l) stage_full(0, 0); else stage_tail(0, 0);

    // Q B-frags in registers: bq[nt][kc] = B[k=kc*32+q4*8+j][n=m16]
    bf8_t bq[2][2];
    #pragma unroll
    for (int nt = 0; nt < 2; nt++) {
        int qrow = q0 + wv * 32 + nt * 16 + m16;
        #pragma unroll
        for (int kc = 0; kc < 2; kc++) {
            bf8_t v = (bf8_t)0;
            if (qrow < l)
                v = *(const bf8_t*)(qkv + (long)(seq0 + qrow) * QKV_LD + h * HDIM + kc * 32 + q4 * 8);
            bq[nt][kc] = v;
        }
    }

    f4_t oacc[2][4] = {};
    float m_s[2] = {-1e30f, -1e30f};
    float l_s[2] = {0.0f, 0.0f};

    const int ksw0 = (q4 ^ (m16 & 7)) * 8;        // slot of global chunk q4
    const int ksw1 = ((4 + q4) ^ (m16 & 7)) * 8;  // slot of global chunk 4+q4

    asm volatile("s_waitcnt vmcnt(0) lgkmcnt(0)" ::: "memory");
    __builtin_amdgcn_s_barrier();

    for (int it = 0; it < NT; ++it) {
        const int kv0 = it << 6;
        const bool full = (kv0 + 64 <= l);
        if (it + 1 < NT) {                       // issue next tile's loads NOW
            int kvn = kv0 + 64;
            if (kvn + 64 <= l) stage_full(kvn, (it + 1) & 1);
            else stage_tail(kvn, (it + 1) & 1);
        }
        const __hip_bfloat16* Kb = Ks[it & 1];
        const __hip_bfloat16* Vb = Vs[it & 1];

        // S^T = K.Q^T : S[nt][mt] holds S^T[key=mt*16+q4*4+r][qrow=m16]
        f4_t S[2][4];
        __builtin_amdgcn_s_setprio(1);
        #pragma unroll
        for (int mt = 0; mt < 4; mt++) {
            const __hip_bfloat16* krow = &Kb[(mt * 16 + m16) * 64];
            bf8_t ak0 = *(const bf8_t*)(krow + ksw0);
            bf8_t ak1 = *(const bf8_t*)(krow + ksw1);
            #pragma unroll
            for (int nt = 0; nt < 2; nt++) {
                f4_t a = {};
                a = mfma16x32(ak0, bq[nt][0], a);
                a = mfma16x32(ak1, bq[nt][1], a);
                S[nt][mt] = a;
            }
        }
        __builtin_amdgcn_s_setprio(0);

        if (!full) {
            #pragma unroll
            for (int mt = 0; mt < 4; mt++) {
                #pragma unroll
                for (int r = 0; r < 4; r++) {
                    bool valid = (kv0 + mt * 16 + q4 * 4 + r) < l;
                    #pragma unroll
                    for (int nt = 0; nt < 2; nt++)
                        if (!valid) S[nt][mt][r] = -1e30f;
                }
            }
        }

        // online softmax (base-2 domain; log2e folded into Wq/bq) + defer-max (THR=8)
        // tree reductions: fmax depth 4, ls partials depth ~6
        #pragma unroll
        for (int nt = 0; nt < 2; nt++) {
            float pm[4];
            #pragma unroll
            for (int mt = 0; mt < 4; mt++)
                pm[mt] = fmaxf(fmaxf(S[nt][mt][0], S[nt][mt][1]),
                               fmaxf(S[nt][mt][2], S[nt][mt][3]));
            float mx = fmaxf(fmaxf(pm[0], pm[1]), fmaxf(pm[2], pm[3]));
            mx = fmaxf(mx, __shfl_xor(mx, 16));
            mx = fmaxf(mx, __shfl_xor(mx, 32));
            if (!__all(mx - m_s[nt] <= 8.0f)) {
                float mn = fmaxf(m_s[nt], mx);
                float al = exp2f(m_s[nt] - mn);
                m_s[nt] = mn;
                l_s[nt] *= al;
                #pragma unroll
                for (int dt = 0; dt < 4; dt++)
                    #pragma unroll
                    for (int r = 0; r < 4; r++)
                        oacc[nt][dt][r] *= al;
            }
            float mcur = m_s[nt];
            float ps[4];
            #pragma unroll
            for (int mt = 0; mt < 4; mt++) {
                f4_t p;
                p[0] = exp2f(S[nt][mt][0] - mcur);
                p[1] = exp2f(S[nt][mt][1] - mcur);
                p[2] = exp2f(S[nt][mt][2] - mcur);
                p[3] = exp2f(S[nt][mt][3] - mcur);
                S[nt][mt] = p;
                ps[mt] = (p[0] + p[1]) + (p[2] + p[3]);
            }
            l_s[nt] += (ps[0] + ps[1]) + (ps[2] + ps[3]);
        }

        // O^T += V^T . P^T  (A=V^T from swizzled LDS, B=P^T packed in-place)
        __builtin_amdgcn_s_setprio(1);
        #pragma unroll
        for (int mt = 0; mt < 4; mt++) {
            bf4_t bp0 = pk4(S[0][mt]);
            bf4_t bp1 = pk4(S[1][mt]);
            const int vsw = ((mt * 2 + (q4 >> 1)) ^ (m16 & 7)) * 8 + (q4 & 1) * 4;
            #pragma unroll
            for (int dt = 0; dt < 4; dt++) {
                bf4_t av = *(const bf4_t*)&Vb[(dt * 16 + m16) * 64 + vsw];
                oacc[0][dt] = mfma16x16(av, bp0, oacc[0][dt]);
                oacc[1][dt] = mfma16x16(av, bp1, oacc[1][dt]);
            }
        }
        __builtin_amdgcn_s_setprio(0);

        if (it + 1 < NT) {
            // wait for next tile's staging (issued before compute -> mostly landed)
            // and make all waves' LDS writes visible; ONE barrier per tile.
            asm volatile("s_waitcnt vmcnt(0) lgkmcnt(0)" ::: "memory");
            __builtin_amdgcn_s_barrier();
        }
    }

    // finalize
    #pragma unroll
    for (int nt = 0; nt < 2; nt++) {
        float ls = l_s[nt];
        ls += __shfl_xor(ls, 16);
        ls += __shfl_xor(ls, 32);
        float inv = 1.0f / ls;
        int qrow = q0 + wv * 32 + nt * 16 + m16;
        if (qrow < l) {
            #pragma unroll
            for (int dt = 0; dt < 4; dt++) {
                f4_t o;
                #pragma unroll
                for (int r = 0; r < 4; r++)
                    o[r] = oacc[nt][dt][r] * inv;
                *(bf4_t*)&obuf[(long)(seq0 + qrow) * E_DIM + h * HDIM + dt * 16 + q4 * 4] = pk4(o);
            }
        }
    }
}

// ---------------- launch ----------------
extern "C" void kernel_launch(void* const* d_in, const int* in_sizes, int n_in,
                              void* d_out, int out_size, void* d_ws, size_t ws_size,
                              hipStream_t stream) {
    const int E = E_DIM;
    const int T = in_sizes[0] / E;      // 8192
    const int B = in_sizes[1] - 1;      // 8

    const float* x  = (const float*)d_in[0];
    const int*   cu = (const int*)d_in[1];
    const float* Wq = (const float*)d_in[3];
    const float* bq = (const float*)d_in[4];
    const float* Wk = (const float*)d_in[5];
    const float* bk = (const float*)d_in[6];
    const float* Wv = (const float*)d_in[7];
    const float* bv = (const float*)d_in[8];
    const float* Wo = (const float*)d_in[9];
    const float* bo = (const float*)d_in[10];

    char* ws = (char*)d_ws;
    size_t off = 0;
    auto alloc = [&](size_t bytes) -> void* {
        void* p = ws + off;
        off = (off + bytes + 255) & ~(size_t)255;
        return p;
    };
    __hip_bfloat16* xbf   = (__hip_bfloat16*)alloc((size_t)T * E * 2);
    __hip_bfloat16* wqkv  = (__hip_bfloat16*)alloc((size_t)3 * E * E * 2);
    __hip_bfloat16* wobf  = (__hip_bfloat16*)alloc((size_t)E * E * 2);
    float*          bqkv  = (float*)alloc((size_t)3 * E * 4);
    __hip_bfloat16* qkvb  = (__hip_bfloat16*)alloc((size_t)T * 3 * E * 2);
    __hip_bfloat16* vt    = (__hip_bfloat16*)alloc((size_t)E * T * 2);
    __hip_bfloat16* obuf  = xbf;  // alias: x_bf dead after QKV GEMM

    long nx8 = (long)T * E / 8;
    long nw8 = (long)E * E / 8;
    long nb8 = (long)3 * E / 8;
    long total = nx8 + 4 * nw8 + nb8;
    int pblocks = (int)((total + 255) / 256);
    prep_kernel<<<pblocks, 256, 0, stream>>>(x, Wq, Wk, Wv, Wo, bq, bk, bv,
                                             xbf, wqkv, wobf, bqkv, nx8, nw8, nb8);

    // QKV projection: 256^2-tile pipelined GEMM; RoPE fused into q/k epilogue
    // (HW v_sin/v_cos), V columns written transposed to vt. rope_kernel deleted.
    gemm256<<<(T / 256) * (3 * E / 256), 512, 0, stream>>>(
        xbf, wqkv, bqkv, qkvb, vt, T, cu, B, T, 3 * E, E, 3 * E);

    // 128-row q-tiles: upper bound on sum of per-seq ceil(l/128)
    int qtiles_ub = T / 128 + B;
    attn_kernel<<<qtiles_ub * NHEADS, 256, 0, stream>>>(qkvb, vt, cu, obuf, B, T);

    // output projection: N=1280 -> only 160 blocks at 256^2; keep 128^2 (640 blocks)
    gemm_nt<false><<<dim3(E / 128, T / 128), 256, 0, stream>>>(
        obuf, wobf, bo, d_out, T, E, E, E);
}

// Round 10
// 378.399 us; speedup vs baseline: 1.1627x; 1.0233x over previous
//
#include <hip/hip_runtime.h>
#include <hip/hip_bf16.h>
#include <cstdint>

#define E_DIM   1280
#define NHEADS  20
#define HDIM    64
#define QKV_LD  3840   // 3*E

typedef __attribute__((ext_vector_type(8))) short bf8_t;   // 8 bf16 (4 VGPRs)
typedef __attribute__((ext_vector_type(4))) short bf4_t;   // 4 bf16 (2 VGPRs)
typedef __attribute__((ext_vector_type(4))) float f4_t;    // MFMA accumulator

__device__ __forceinline__ short f2bs(float f) {
    union { __hip_bfloat16 h; short s; } u;
    u.h = __float2bfloat16(f);
    return u.s;
}

// hardware packed f32x2 -> bf16x2 (RNE), T12 recipe: no builtin on gfx950
__device__ __forceinline__ bf4_t pk4(f4_t s) {
    union { bf4_t v; uint32_t u[2]; } r;
    asm("v_cvt_pk_bf16_f32 %0, %1, %2" : "=v"(r.u[0]) : "v"(s[0]), "v"(s[1]));
    asm("v_cvt_pk_bf16_f32 %0, %1, %2" : "=v"(r.u[1]) : "v"(s[2]), "v"(s[3]));
    return r.v;
}

__device__ __forceinline__ f4_t mfma16x32(bf8_t a, bf8_t b, f4_t c) {
    return __builtin_amdgcn_mfma_f32_16x16x32_bf16(a, b, c, 0, 0, 0);
}
__device__ __forceinline__ f4_t mfma16x16(bf4_t a, bf4_t b, f4_t c) {
    return __builtin_amdgcn_mfma_f32_16x16x16bf16_1k(a, b, c, 0, 0, 0);
}

// async global->LDS, 16B per lane. LDS dest is wave-uniform base + lane*16.
__device__ __forceinline__ void gl_lds16(const void* g, void* l) {
    auto gp = reinterpret_cast<__attribute__((address_space(1))) unsigned int*>(
        reinterpret_cast<uintptr_t>(g));
    auto lp = reinterpret_cast<__attribute__((address_space(3))) unsigned int*>(
        reinterpret_cast<uintptr_t>(l));
    __builtin_amdgcn_global_load_lds(gp, lp, 16, 0, 0);
}

// ---------------- prep: casts + weight concat + bias concat ----------------
// Wq/bq scale = d^-0.5 * log2(e): softmax computed in base-2 domain (exp2f).
#define QSCALE 0.18033688011112042f

__device__ __forceinline__ void cvt8(__hip_bfloat16* dst, const float* src, float sc) {
    float4 a = *(const float4*)src;
    float4 b = *(const float4*)(src + 4);
    bf8_t v;
    v[0] = f2bs(a.x * sc); v[1] = f2bs(a.y * sc); v[2] = f2bs(a.z * sc); v[3] = f2bs(a.w * sc);
    v[4] = f2bs(b.x * sc); v[5] = f2bs(b.y * sc); v[6] = f2bs(b.z * sc); v[7] = f2bs(b.w * sc);
    *(bf8_t*)dst = v;
}

__global__ __launch_bounds__(256) void prep_kernel(
    const float* __restrict__ x,
    const float* __restrict__ wq, const float* __restrict__ wk,
    const float* __restrict__ wv, const float* __restrict__ wo,
    const float* __restrict__ bq, const float* __restrict__ bk, const float* __restrict__ bv,
    __hip_bfloat16* __restrict__ xbf, __hip_bfloat16* __restrict__ wqkv,
    __hip_bfloat16* __restrict__ wobf, float* __restrict__ bqkv,
    long nx8, long nw8, long nb8)
{
    long u = (long)blockIdx.x * 256 + threadIdx.x;
    if (u < nx8) { cvt8(xbf + u * 8, x + u * 8, 1.0f); return; }
    u -= nx8;
    if (u < 3 * nw8) {
        long e = u * 8;
        long w1 = nw8 * 8;
        const float* src; float sc;
        if (e < w1)            { src = wq + e;           sc = QSCALE; }
        else if (e < 2 * w1)   { src = wk + (e - w1);    sc = 1.0f; }
        else                   { src = wv + (e - 2*w1);  sc = 1.0f; }
        cvt8(wqkv + e, src, sc);
        return;
    }
    u -= 3 * nw8;
    if (u < nw8) { cvt8(wobf + u * 8, wo + u * 8, 1.0f); return; }
    u -= nw8;
    if (u < nb8) {
        long e = u * 8;
        #pragma unroll
        for (int j = 0; j < 8; j++) {
            long i = e + j;
            float v;
            if (i < E_DIM)           v = bq[i] * QSCALE;
            else if (i < 2 * E_DIM)  v = bk[i - E_DIM];
            else                     v = bv[i - 2 * E_DIM];
            bqkv[i] = v;
        }
    }
}

// ---------------- m97-style NT GEMM (output proj): C = A*B^T + bias ----------------
template<bool BF16_OUT>
__global__ __launch_bounds__(256, 3) void gemm_nt(
    const __hip_bfloat16* __restrict__ A, const __hip_bfloat16* __restrict__ Bw,
    const float* __restrict__ bias, void* __restrict__ Cout,
    int M, int N, int K, int ldc)
{
    __shared__ __align__(16) __hip_bfloat16 As[128 * 32];
    __shared__ __align__(16) __hip_bfloat16 Bs[128 * 32];
    const int t = threadIdx.x;
    const int wv = t >> 6;
    const int ln = t & 63;
    const int m16 = ln & 15, q4 = ln >> 4;
    const int row0 = blockIdx.y * 128, col0 = blockIdx.x * 128;
    const int wm = (wv >> 1) * 64, wn = (wv & 1) * 64;

    f4_t acc[4][4] = {};

    for (int k0 = 0; k0 < K; k0 += 32) {
        #pragma unroll
        for (int i = 0; i < 2; i++) {
            int s = i * 256 + t;
            int r = s >> 2, c = s & 3;
            gl_lds16(A + (size_t)(row0 + r) * K + k0 + c * 8,
                     As + (size_t)(i * 256 + wv * 64) * 8);
        }
        #pragma unroll
        for (int i = 0; i < 2; i++) {
            int s = i * 256 + t;
            int r = s >> 2, c = s & 3;
            gl_lds16(Bw + (size_t)(col0 + r) * K + k0 + c * 8,
                     Bs + (size_t)(i * 256 + wv * 64) * 8);
        }
        __syncthreads();
        bf8_t af[4], bfr[4];
        #pragma unroll
        for (int mt = 0; mt < 4; mt++)
            af[mt] = *(const bf8_t*)&As[(wm + mt * 16 + m16) * 32 + q4 * 8];
        #pragma unroll
        for (int nt = 0; nt < 4; nt++)
            bfr[nt] = *(const bf8_t*)&Bs[(wn + nt * 16 + m16) * 32 + q4 * 8];
        #pragma unroll
        for (int mt = 0; mt < 4; mt++)
            #pragma unroll
            for (int nt = 0; nt < 4; nt++)
                acc[mt][nt] = mfma16x32(af[mt], bfr[nt], acc[mt][nt]);
        __syncthreads();
    }

    #pragma unroll
    for (int nt = 0; nt < 4; nt++) {
        int cg = col0 + wn + nt * 16 + m16;
        float bv = bias[cg];
        #pragma unroll
        for (int mt = 0; mt < 4; mt++) {
            #pragma unroll
            for (int r = 0; r < 4; r++) {
                int rg = row0 + wm + mt * 16 + q4 * 4 + r;
                float v = acc[mt][nt][r] + bv;
                if constexpr (BF16_OUT)
                    ((__hip_bfloat16*)Cout)[(long)rg * ldc + cg] = __float2bfloat16(v);
                else
                    ((float*)Cout)[(long)rg * ldc + cg] = v;
            }
        }
    }
}

// ---------------- 256x256 pipelined NT GEMM for QKV (T1+T2+T3/T4+T5 stack) --------
// Round-9 lesson: fusing RoPE into this epilogue pushed VGPR 112->128 (the 4-wave/SIMD
// cliff) and cost +25us in gemm256 for a 26us kernel saved -> net negative. Reverted
// to the round-7 form: V-column blocks (col0 >= 2E) write TRANSPOSED to vt, q/k
// columns get bias only; RoPE is a standalone kernel with HW trig (proven numerics).
__global__ __launch_bounds__(512, 2) void gemm256(
    const __hip_bfloat16* __restrict__ A, const __hip_bfloat16* __restrict__ Bw,
    const float* __restrict__ bias, __hip_bfloat16* __restrict__ Cout,
    __hip_bfloat16* __restrict__ vtout, int Tdim,
    int M, int N, int K, int ldc)
{
    __shared__ __align__(16) __hip_bfloat16 As[2][256 * 64];  // 2 x 32 KB
    __shared__ __align__(16) __hip_bfloat16 Bs[2][256 * 64];  // 2 x 32 KB

    const int t = threadIdx.x;
    const int wv = t >> 6, ln = t & 63;
    const int m16 = ln & 15, q4 = ln >> 4;
    const int wr = wv >> 2, wc = wv & 3;   // 2 x 4 wave grid

    const int gx = N >> 8;
    const int nwg = gridDim.x;
    const int id = blockIdx.x;
    const int swz = ((nwg & 7) == 0) ? (id & 7) * (nwg >> 3) + (id >> 3) : id;  // T1 (bijective: nwg%8==0)
    const int col0 = (swz % gx) << 8;
    const int row0 = (swz / gx) << 8;

    const int NT = K >> 6;   // K-tiles of 64

    // stage one 256x64 tile: linear LDS dest (slot order), inverse-swizzled global src
    auto stage = [&](const __hip_bfloat16* src, __hip_bfloat16* dst) {
        #pragma unroll
        for (int i = 0; i < 4; i++) {
            int s = i * 512 + t;
            int r = s >> 3, c = (s & 7) ^ (r & 7);
            gl_lds16(src + (size_t)r * K + c * 8,
                     (char*)dst + (size_t)(i * 512 + wv * 64) * 16);
        }
    };

    // prologue: tiles 0 and 1
    stage(A  + (size_t)row0 * K,      &As[0][0]);
    stage(Bw + (size_t)col0 * K,      &Bs[0][0]);
    if (NT > 1) {
        stage(A  + (size_t)row0 * K + 64, &As[1][0]);
        stage(Bw + (size_t)col0 * K + 64, &Bs[1][0]);
        asm volatile("s_waitcnt vmcnt(8)" ::: "memory");   // tile 0 landed; tile 1 in flight
    } else {
        asm volatile("s_waitcnt vmcnt(0)" ::: "memory");
    }
    __builtin_amdgcn_s_barrier();

    f4_t acc[8][4] = {};

    for (int kt = 0; kt < NT; kt++) {
        const __hip_bfloat16* Ab = &As[kt & 1][0];
        const __hip_bfloat16* Bb = &Bs[kt & 1][0];

        auto lda = [&](const __hip_bfloat16* base, int r, int kc) {
            return *(const bf8_t*)&base[r * 64 + ((((kc << 2) | q4) ^ (r & 7)) << 3)];
        };

        bf8_t afr[4][2], bf0[2][2], bf1[2][2];
        // Q(mh0,nh0): af half 0 (8 reads) + bf half 0 (4 reads)
        #pragma unroll
        for (int mt = 0; mt < 4; mt++)
            #pragma unroll
            for (int kc = 0; kc < 2; kc++)
                afr[mt][kc] = lda(Ab, wr * 128 + mt * 16 + m16, kc);
        #pragma unroll
        for (int nt = 0; nt < 2; nt++)
            #pragma unroll
            for (int kc = 0; kc < 2; kc++)
                bf0[nt][kc] = lda(Bb, wc * 64 + nt * 16 + m16, kc);

        __builtin_amdgcn_s_setprio(1);
        #pragma unroll
        for (int mt = 0; mt < 4; mt++)
            #pragma unroll
            for (int nt = 0; nt < 2; nt++)
                #pragma unroll
                for (int kc = 0; kc < 2; kc++)
                    acc[mt][nt] = mfma16x32(afr[mt][kc], bf0[nt][kc], acc[mt][nt]);
        __builtin_amdgcn_s_setprio(0);

        // Q(mh0,nh1): new bf half 1 (4 reads)
        #pragma unroll
        for (int nt = 0; nt < 2; nt++)
            #pragma unroll
            for (int kc = 0; kc < 2; kc++)
                bf1[nt][kc] = lda(Bb, wc * 64 + (2 + nt) * 16 + m16, kc);

        __builtin_amdgcn_s_setprio(1);
        #pragma unroll
        for (int mt = 0; mt < 4; mt++)
            #pragma unroll
            for (int nt = 0; nt < 2; nt++)
                #pragma unroll
                for (int kc = 0; kc < 2; kc++)
                    acc[mt][2 + nt] = mfma16x32(afr[mt][kc], bf1[nt][kc], acc[mt][2 + nt]);
        __builtin_amdgcn_s_setprio(0);

        // Q(mh1,nh1): new af half 1 (8 reads)
        #pragma unroll
        for (int mt = 0; mt < 4; mt++)
            #pragma unroll
            for (int kc = 0; kc < 2; kc++)
                afr[mt][kc] = lda(Ab, wr * 128 + (4 + mt) * 16 + m16, kc);

        __builtin_amdgcn_s_setprio(1);
        #pragma unroll
        for (int mt = 0; mt < 4; mt++)
            #pragma unroll
            for (int nt = 0; nt < 2; nt++)
                #pragma unroll
                for (int kc = 0; kc < 2; kc++)
                    acc[4 + mt][2 + nt] = mfma16x32(afr[mt][kc], bf1[nt][kc], acc[4 + mt][2 + nt]);
        __builtin_amdgcn_s_setprio(0);

        // Q(mh1,nh0): bf half 0 still live
        __builtin_amdgcn_s_setprio(1);
        #pragma unroll
        for (int mt = 0; mt < 4; mt++)
            #pragma unroll
            for (int nt = 0; nt < 2; nt++)
                #pragma unroll
                for (int kc = 0; kc < 2; kc++)
                    acc[4 + mt][nt] = mfma16x32(afr[mt][kc], bf0[nt][kc], acc[4 + mt][nt]);
        __builtin_amdgcn_s_setprio(0);

        // all reads of slot kt&1 done (per-wave lgkmcnt before MFMA; barrier -> all waves)
        asm volatile("s_waitcnt lgkmcnt(0)" ::: "memory");
        __builtin_amdgcn_s_barrier();

        if (kt + 2 < NT) {   // restage the just-freed slot for tile kt+2
            stage(A  + (size_t)row0 * K + (size_t)(kt + 2) * 64, &As[kt & 1][0]);
            stage(Bw + (size_t)col0 * K + (size_t)(kt + 2) * 64, &Bs[kt & 1][0]);
        }
        if (kt + 1 < NT) {
            if (kt + 2 < NT)
                asm volatile("s_waitcnt vmcnt(8)" ::: "memory");  // tile kt+1 landed; kt+2 in flight
            else
                asm volatile("s_waitcnt vmcnt(0)" ::: "memory");  // drain last tile
            __builtin_amdgcn_s_barrier();
        }
    }

    if (col0 >= 2 * E_DIM) {
        // V block: write transposed into vt, 8B bf4 per (mt,nt) (4 consecutive tokens)
        #pragma unroll
        for (int nt = 0; nt < 4; nt++) {
            int cg = col0 + wc * 64 + nt * 16 + m16;
            float bval = bias[cg];
            int vrow = cg - 2 * E_DIM;
            #pragma unroll
            for (int mt = 0; mt < 8; mt++) {
                int rg0 = row0 + wr * 128 + mt * 16 + q4 * 4;
                f4_t vv;
                #pragma unroll
                for (int r = 0; r < 4; r++) vv[r] = acc[mt][nt][r] + bval;
                *(bf4_t*)&vtout[(long)vrow * Tdim + rg0] = pk4(vv);
            }
        }
    } else {
        #pragma unroll
        for (int nt = 0; nt < 4; nt++) {
            int cg = col0 + wc * 64 + nt * 16 + m16;
            float bval = bias[cg];
            #pragma unroll
            for (int mt = 0; mt < 8; mt++) {
                #pragma unroll
                for (int r = 0; r < 4; r++) {
                    int rg = row0 + wr * 128 + mt * 16 + q4 * 4 + r;
                    Cout[(long)rg * ldc + cg] = __float2bfloat16(acc[mt][nt][r] + bval);
                }
            }
        }
    }
}

// ---------------- RoPE (in place on q,k sections of qkv) ----------------
// HW trig in revolutions domain (v_sin/v_cos + fract range-reduction) — numerics
// proven in round 9's pass. Replaces sincosf, whose Payne-Hanek slow path (angles
// up to 1279 rad) costs scratch + VALU far beyond this kernel's ~13us HBM floor.
__global__ __launch_bounds__(256) void rope_kernel(
    __hip_bfloat16* __restrict__ qkv, const int* __restrict__ cu, int B, int T)
{
    long idx = (long)blockIdx.x * 256 + threadIdx.x;
    int i = idx & 31;
    long r = idx >> 5;
    int h = (int)(r % NHEADS);
    int tok = (int)(r / NHEADS);
    if (tok >= T) return;
    int pos = tok;
    for (int b = 1; b <= B; b++) if (tok >= cu[b]) pos = tok - cu[b];
    // revolutions per position: exp2(-i*log2(10000)/32 - log2(2*pi))
    float rev = (float)pos * exp2f(-(float)i * 0.41524100558003436f
                                   - 2.6514961294723187f);
    rev = rev - floorf(rev);
    float s, c;
    asm("v_sin_f32 %0, %1" : "=v"(s) : "v"(rev));
    asm("v_cos_f32 %0, %1" : "=v"(c) : "v"(rev));
    long base = (long)tok * QKV_LD + h * HDIM + i;
    {
        float q1 = __bfloat162float(qkv[base]);
        float q2 = __bfloat162float(qkv[base + 32]);
        qkv[base]      = __float2bfloat16(q1 * c - q2 * s);
        qkv[base + 32] = __float2bfloat16(q2 * c + q1 * s);
    }
    {
        long kb = base + E_DIM;
        float k1 = __bfloat162float(qkv[kb]);
        float k2 = __bfloat162float(qkv[kb + 32]);
        qkv[kb]      = __float2bfloat16(k1 * c - k2 * s);
        qkv[kb + 32] = __float2bfloat16(k2 * c + k1 * s);
    }
}

// ---------------- flash attention: round-7 structure (KVBLK=64, 2-phase, 4 blk/CU,
// longest-first). Byte-identical to the round-7 kernel for clean attribution. ----
__global__ __launch_bounds__(256, 4) void attn_kernel(
    const __hip_bfloat16* __restrict__ qkv, const __hip_bfloat16* __restrict__ vt,
    const int* __restrict__ cu, __hip_bfloat16* __restrict__ obuf, int B, int T)
{
    __shared__ __align__(16) __hip_bfloat16 Ks[2][64 * 64];  // [key][d] swizzled, 2x8 KB
    __shared__ __align__(16) __hip_bfloat16 Vs[2][64 * 64];  // [d][key] swizzled, 2x8 KB

    int idx = blockIdx.x;
    int h = idx % NHEADS;
    int gt = idx / NHEADS;
    // longest-first: sequences sorted ascending in cu -> scan in REVERSE
    int b = B - 1, l = 0, seq0 = 0;
    for (; b >= 0; --b) {
        seq0 = cu[b];
        l = cu[b + 1] - seq0;
        int ntile = (l + 127) >> 7;
        if (gt < ntile) break;
        gt -= ntile;
    }
    if (b < 0) return;
    int q0 = gt * 128;
    const int NT = (l + 63) >> 6;

    const int t = threadIdx.x;
    const int wv = t >> 6, ln = t & 63;
    const int m16 = ln & 15, q4 = ln >> 4;

    // K: slot s2 -> key s2>>3, chunk (s2&7)^(key&7); V: d s2>>3, chunk (s2&7)^(d&7)
    auto stage_full = [&](int kv0n, int bi) {
        #pragma unroll
        for (int i = 0; i < 2; i++) {
            int s2 = i * 256 + t;
            int key = s2 >> 3, cg = (s2 & 7) ^ (key & 7);
            gl_lds16(qkv + (long)(seq0 + kv0n + key) * QKV_LD + E_DIM + h * HDIM + cg * 8,
                     (char*)&Ks[bi][0] + (size_t)(i * 256 + wv * 64) * 16);
        }
        #pragma unroll
        for (int i = 0; i < 2; i++) {
            int s2 = i * 256 + t;
            int d = s2 >> 3, cg = (s2 & 7) ^ (d & 7);
            gl_lds16(vt + (long)(h * HDIM + d) * T + seq0 + kv0n + cg * 8,
                     (char*)&Vs[bi][0] + (size_t)(i * 256 + wv * 64) * 16);
        }
    };
    auto stage_tail = [&](int kv0n, int bi) {   // dead in this workload (l % 128 == 0)
        #pragma unroll
        for (int i = 0; i < 2; i++) {
            int s2 = i * 256 + t;
            int key = s2 >> 3, c = s2 & 7;
            bf8_t v = (bf8_t)0;
            if (kv0n + key < l)
                v = *(const bf8_t*)(qkv + (long)(seq0 + kv0n + key) * QKV_LD + E_DIM + h * HDIM + c * 8);
            *(bf8_t*)&Ks[bi][key * 64 + (c ^ (key & 7)) * 8] = v;
        }
        #pragma unroll
        for (int i = 0; i < 2; i++) {
            int s2 = i * 256 + t;
            int d = s2 >> 3, c = s2 & 7;
            bf8_t v = (bf8_t)0;
            int tb = kv0n + c * 8;
            #pragma unroll
            for (int u = 0; u < 8; u++)
                if (tb + u < l)
                    v[u] = *(const short*)&vt[(long)(h * HDIM + d) * T + seq0 + tb + u];
            *(bf8_t*)&Vs[bi][d * 64 + (c ^ (d & 7)) * 8] = v;
        }
    };

    // prologue: issue staging of tile 0 first, then load Q while it flies
    if (64 <= l) stage_full(0, 0); else stage_tail(0, 0);

    // Q B-frags in registers: bq[nt][kc] = B[k=kc*32+q4*8+j][n=m16]
    bf8_t bq[2][2];
    #pragma unroll
    for (int nt = 0; nt < 2; nt++) {
        int qrow = q0 + wv * 32 + nt * 16 + m16;
        #pragma unroll
        for (int kc = 0; kc < 2; kc++) {
            bf8_t v = (bf8_t)0;
            if (qrow < l)
                v = *(const bf8_t*)(qkv + (long)(seq0 + qrow) * QKV_LD + h * HDIM + kc * 32 + q4 * 8);
            bq[nt][kc] = v;
        }
    }

    f4_t oacc[2][4] = {};
    float m_s[2] = {-1e30f, -1e30f};
    float l_s[2] = {0.0f, 0.0f};

    const int ksw0 = (q4 ^ (m16 & 7)) * 8;        // slot of global chunk q4
    const int ksw1 = ((4 + q4) ^ (m16 & 7)) * 8;  // slot of global chunk 4+q4

    asm volatile("s_waitcnt vmcnt(0) lgkmcnt(0)" ::: "memory");
    __builtin_amdgcn_s_barrier();

    for (int it = 0; it < NT; ++it) {
        const int kv0 = it << 6;
        const bool full = (kv0 + 64 <= l);
        if (it + 1 < NT) {                       // issue next tile's loads NOW
            int kvn = kv0 + 64;
            if (kvn + 64 <= l) stage_full(kvn, (it + 1) & 1);
            else stage_tail(kvn, (it + 1) & 1);
        }
        const __hip_bfloat16* Kb = Ks[it & 1];
        const __hip_bfloat16* Vb = Vs[it & 1];

        // S^T = K.Q^T : S[nt][mt] holds S^T[key=mt*16+q4*4+r][qrow=m16]
        f4_t S[2][4];
        __builtin_amdgcn_s_setprio(1);
        #pragma unroll
        for (int mt = 0; mt < 4; mt++) {
            const __hip_bfloat16* krow = &Kb[(mt * 16 + m16) * 64];
            bf8_t ak0 = *(const bf8_t*)(krow + ksw0);
            bf8_t ak1 = *(const bf8_t*)(krow + ksw1);
            #pragma unroll
            for (int nt = 0; nt < 2; nt++) {
                f4_t a = {};
                a = mfma16x32(ak0, bq[nt][0], a);
                a = mfma16x32(ak1, bq[nt][1], a);
                S[nt][mt] = a;
            }
        }
        __builtin_amdgcn_s_setprio(0);

        if (!full) {
            #pragma unroll
            for (int mt = 0; mt < 4; mt++) {
                #pragma unroll
                for (int r = 0; r < 4; r++) {
                    bool valid = (kv0 + mt * 16 + q4 * 4 + r) < l;
                    #pragma unroll
                    for (int nt = 0; nt < 2; nt++)
                        if (!valid) S[nt][mt][r] = -1e30f;
                }
            }
        }

        // online softmax (base-2 domain; log2e folded into Wq/bq) + defer-max (THR=8)
        // tree reductions: fmax depth 4, ls partials depth ~6
        #pragma unroll
        for (int nt = 0; nt < 2; nt++) {
            float pm[4];
            #pragma unroll
            for (int mt = 0; mt < 4; mt++)
                pm[mt] = fmaxf(fmaxf(S[nt][mt][0], S[nt][mt][1]),
                               fmaxf(S[nt][mt][2], S[nt][mt][3]));
            float mx = fmaxf(fmaxf(pm[0], pm[1]), fmaxf(pm[2], pm[3]));
            mx = fmaxf(mx, __shfl_xor(mx, 16));
            mx = fmaxf(mx, __shfl_xor(mx, 32));
            if (!__all(mx - m_s[nt] <= 8.0f)) {
                float mn = fmaxf(m_s[nt], mx);
                float al = exp2f(m_s[nt] - mn);
                m_s[nt] = mn;
                l_s[nt] *= al;
                #pragma unroll
                for (int dt = 0; dt < 4; dt++)
                    #pragma unroll
                    for (int r = 0; r < 4; r++)
                        oacc[nt][dt][r] *= al;
            }
            float mcur = m_s[nt];
            float ps[4];
            #pragma unroll
            for (int mt = 0; mt < 4; mt++) {
                f4_t p;
                p[0] = exp2f(S[nt][mt][0] - mcur);
                p[1] = exp2f(S[nt][mt][1] - mcur);
                p[2] = exp2f(S[nt][mt][2] - mcur);
                p[3] = exp2f(S[nt][mt][3] - mcur);
                S[nt][mt] = p;
                ps[mt] = (p[0] + p[1]) + (p[2] + p[3]);
            }
            l_s[nt] += (ps[0] + ps[1]) + (ps[2] + ps[3]);
        }

        // O^T += V^T . P^T  (A=V^T from swizzled LDS, B=P^T packed in-place)
        __builtin_amdgcn_s_setprio(1);
        #pragma unroll
        for (int mt = 0; mt < 4; mt++) {
            bf4_t bp0 = pk4(S[0][mt]);
            bf4_t bp1 = pk4(S[1][mt]);
            const int vsw = ((mt * 2 + (q4 >> 1)) ^ (m16 & 7)) * 8 + (q4 & 1) * 4;
            #pragma unroll
            for (int dt = 0; dt < 4; dt++) {
                bf4_t av = *(const bf4_t*)&Vb[(dt * 16 + m16) * 64 + vsw];
                oacc[0][dt] = mfma16x16(av, bp0, oacc[0][dt]);
                oacc[1][dt] = mfma16x16(av, bp1, oacc[1][dt]);
            }
        }
        __builtin_amdgcn_s_setprio(0);

        if (it + 1 < NT) {
            // wait for next tile's staging (issued before compute -> mostly landed)
            // and make all waves' LDS writes visible; ONE barrier per tile.
            asm volatile("s_waitcnt vmcnt(0) lgkmcnt(0)" ::: "memory");
            __builtin_amdgcn_s_barrier();
        }
    }

    // finalize
    #pragma unroll
    for (int nt = 0; nt < 2; nt++) {
        float ls = l_s[nt];
        ls += __shfl_xor(ls, 16);
        ls += __shfl_xor(ls, 32);
        float inv = 1.0f / ls;
        int qrow = q0 + wv * 32 + nt * 16 + m16;
        if (qrow < l) {
            #pragma unroll
            for (int dt = 0; dt < 4; dt++) {
                f4_t o;
                #pragma unroll
                for (int r = 0; r < 4; r++)
                    o[r] = oacc[nt][dt][r] * inv;
                *(bf4_t*)&obuf[(long)(seq0 + qrow) * E_DIM + h * HDIM + dt * 16 + q4 * 4] = pk4(o);
            }
        }
    }
}

// ---------------- launch ----------------
extern "C" void kernel_launch(void* const* d_in, const int* in_sizes, int n_in,
                              void* d_out, int out_size, void* d_ws, size_t ws_size,
                              hipStream_t stream) {
    const int E = E_DIM;
    const int T = in_sizes[0] / E;      // 8192
    const int B = in_sizes[1] - 1;      // 8

    const float* x  = (const float*)d_in[0];
    const int*   cu = (const int*)d_in[1];
    const float* Wq = (const float*)d_in[3];
    const float* bq = (const float*)d_in[4];
    const float* Wk = (const float*)d_in[5];
    const float* bk = (const float*)d_in[6];
    const float* Wv = (const float*)d_in[7];
    const float* bv = (const float*)d_in[8];
    const float* Wo = (const float*)d_in[9];
    const float* bo = (const float*)d_in[10];

    char* ws = (char*)d_ws;
    size_t off = 0;
    auto alloc = [&](size_t bytes) -> void* {
        void* p = ws + off;
        off = (off + bytes + 255) & ~(size_t)255;
        return p;
    };
    __hip_bfloat16* xbf   = (__hip_bfloat16*)alloc((size_t)T * E * 2);
    __hip_bfloat16* wqkv  = (__hip_bfloat16*)alloc((size_t)3 * E * E * 2);
    __hip_bfloat16* wobf  = (__hip_bfloat16*)alloc((size_t)E * E * 2);
    float*          bqkv  = (float*)alloc((size_t)3 * E * 4);
    __hip_bfloat16* qkvb  = (__hip_bfloat16*)alloc((size_t)T * 3 * E * 2);
    __hip_bfloat16* vt    = (__hip_bfloat16*)alloc((size_t)E * T * 2);
    __hip_bfloat16* obuf  = xbf;  // alias: x_bf dead after QKV GEMM

    long nx8 = (long)T * E / 8;
    long nw8 = (long)E * E / 8;
    long nb8 = (long)3 * E / 8;
    long total = nx8 + 4 * nw8 + nb8;
    int pblocks = (int)((total + 255) / 256);
    prep_kernel<<<pblocks, 256, 0, stream>>>(x, Wq, Wk, Wv, Wo, bq, bk, bv,
                                             xbf, wqkv, wobf, bqkv, nx8, nw8, nb8);

    // QKV projection: 256^2-tile pipelined GEMM; V columns written transposed to vt
    gemm256<<<(T / 256) * (3 * E / 256), 512, 0, stream>>>(
        xbf, wqkv, bqkv, qkvb, vt, T, T, 3 * E, E, 3 * E);

    // standalone RoPE with HW trig (scratch-free)
    rope_kernel<<<(int)(((long)T * NHEADS * 32) / 256), 256, 0, stream>>>(qkvb, cu, B, T);

    // 128-row q-tiles: upper bound on sum of per-seq ceil(l/128)
    int qtiles_ub = T / 128 + B;
    attn_kernel<<<qtiles_ub * NHEADS, 256, 0, stream>>>(qkvb, vt, cu, obuf, B, T);

    // output projection: N=1280 -> only 160 blocks at 256^2; keep 128^2 (640 blocks)
    gemm_nt<false><<<dim3(E / 128, T / 128), 256, 0, stream>>>(
        obuf, wobf, bo, d_out, T, E, E, E);
}

// Round 11
// 373.187 us; speedup vs baseline: 1.1790x; 1.0140x over previous
//
#include <hip/hip_runtime.h>
#include <hip/hip_bf16.h>
#include <cstdint>

#define E_DIM   1280
#define NHEADS  20
#define HDIM    64
#define QKV_LD  3840   // 3*E

typedef __attribute__((ext_vector_type(8))) short bf8_t;   // 8 bf16 (4 VGPRs)
typedef __attribute__((ext_vector_type(4))) short bf4_t;   // 4 bf16 (2 VGPRs)
typedef __attribute__((ext_vector_type(4))) float f4_t;    // MFMA accumulator

__device__ __forceinline__ short f2bs(float f) {
    union { __hip_bfloat16 h; short s; } u;
    u.h = __float2bfloat16(f);
    return u.s;
}

// hardware packed f32x2 -> bf16x2 (RNE), T12 recipe: no builtin on gfx950
__device__ __forceinline__ bf4_t pk4(f4_t s) {
    union { bf4_t v; uint32_t u[2]; } r;
    asm("v_cvt_pk_bf16_f32 %0, %1, %2" : "=v"(r.u[0]) : "v"(s[0]), "v"(s[1]));
    asm("v_cvt_pk_bf16_f32 %0, %1, %2" : "=v"(r.u[1]) : "v"(s[2]), "v"(s[3]));
    return r.v;
}

__device__ __forceinline__ f4_t mfma16x32(bf8_t a, bf8_t b, f4_t c) {
    return __builtin_amdgcn_mfma_f32_16x16x32_bf16(a, b, c, 0, 0, 0);
}
__device__ __forceinline__ f4_t mfma16x16(bf4_t a, bf4_t b, f4_t c) {
    return __builtin_amdgcn_mfma_f32_16x16x16bf16_1k(a, b, c, 0, 0, 0);
}

// async global->LDS, 16B per lane. LDS dest is wave-uniform base + lane*16.
__device__ __forceinline__ void gl_lds16(const void* g, void* l) {
    auto gp = reinterpret_cast<__attribute__((address_space(1))) unsigned int*>(
        reinterpret_cast<uintptr_t>(g));
    auto lp = reinterpret_cast<__attribute__((address_space(3))) unsigned int*>(
        reinterpret_cast<uintptr_t>(l));
    __builtin_amdgcn_global_load_lds(gp, lp, 16, 0, 0);
}

// ---------------- prep: casts + weight concat + bias concat ----------------
// Wq/bq scale = d^-0.5 * log2(e): softmax computed in base-2 domain (exp2f).
#define QSCALE 0.18033688011112042f

__device__ __forceinline__ void cvt8(__hip_bfloat16* dst, const float* src, float sc) {
    float4 a = *(const float4*)src;
    float4 b = *(const float4*)(src + 4);
    bf8_t v;
    v[0] = f2bs(a.x * sc); v[1] = f2bs(a.y * sc); v[2] = f2bs(a.z * sc); v[3] = f2bs(a.w * sc);
    v[4] = f2bs(b.x * sc); v[5] = f2bs(b.y * sc); v[6] = f2bs(b.z * sc); v[7] = f2bs(b.w * sc);
    *(bf8_t*)dst = v;
}

__global__ __launch_bounds__(256) void prep_kernel(
    const float* __restrict__ x,
    const float* __restrict__ wq, const float* __restrict__ wk,
    const float* __restrict__ wv, const float* __restrict__ wo,
    const float* __restrict__ bq, const float* __restrict__ bk, const float* __restrict__ bv,
    __hip_bfloat16* __restrict__ xbf, __hip_bfloat16* __restrict__ wqkv,
    __hip_bfloat16* __restrict__ wobf, float* __restrict__ bqkv,
    long nx8, long nw8, long nb8)
{
    long u = (long)blockIdx.x * 256 + threadIdx.x;
    if (u < nx8) { cvt8(xbf + u * 8, x + u * 8, 1.0f); return; }
    u -= nx8;
    if (u < 3 * nw8) {
        long e = u * 8;
        long w1 = nw8 * 8;
        const float* src; float sc;
        if (e < w1)            { src = wq + e;           sc = QSCALE; }
        else if (e < 2 * w1)   { src = wk + (e - w1);    sc = 1.0f; }
        else                   { src = wv + (e - 2*w1);  sc = 1.0f; }
        cvt8(wqkv + e, src, sc);
        return;
    }
    u -= 3 * nw8;
    if (u < nw8) { cvt8(wobf + u * 8, wo + u * 8, 1.0f); return; }
    u -= nw8;
    if (u < nb8) {
        long e = u * 8;
        #pragma unroll
        for (int j = 0; j < 8; j++) {
            long i = e + j;
            float v;
            if (i < E_DIM)           v = bq[i] * QSCALE;
            else if (i < 2 * E_DIM)  v = bk[i - E_DIM];
            else                     v = bv[i - 2 * E_DIM];
            bqkv[i] = v;
        }
    }
}

// ---------------- m97-style NT GEMM (output proj): C = A*B^T + bias ----------------
template<bool BF16_OUT>
__global__ __launch_bounds__(256, 3) void gemm_nt(
    const __hip_bfloat16* __restrict__ A, const __hip_bfloat16* __restrict__ Bw,
    const float* __restrict__ bias, void* __restrict__ Cout,
    int M, int N, int K, int ldc)
{
    __shared__ __align__(16) __hip_bfloat16 As[128 * 32];
    __shared__ __align__(16) __hip_bfloat16 Bs[128 * 32];
    const int t = threadIdx.x;
    const int wv = t >> 6;
    const int ln = t & 63;
    const int m16 = ln & 15, q4 = ln >> 4;
    const int row0 = blockIdx.y * 128, col0 = blockIdx.x * 128;
    const int wm = (wv >> 1) * 64, wn = (wv & 1) * 64;

    f4_t acc[4][4] = {};

    for (int k0 = 0; k0 < K; k0 += 32) {
        #pragma unroll
        for (int i = 0; i < 2; i++) {
            int s = i * 256 + t;
            int r = s >> 2, c = s & 3;
            gl_lds16(A + (size_t)(row0 + r) * K + k0 + c * 8,
                     As + (size_t)(i * 256 + wv * 64) * 8);
        }
        #pragma unroll
        for (int i = 0; i < 2; i++) {
            int s = i * 256 + t;
            int r = s >> 2, c = s & 3;
            gl_lds16(Bw + (size_t)(col0 + r) * K + k0 + c * 8,
                     Bs + (size_t)(i * 256 + wv * 64) * 8);
        }
        __syncthreads();
        bf8_t af[4], bfr[4];
        #pragma unroll
        for (int mt = 0; mt < 4; mt++)
            af[mt] = *(const bf8_t*)&As[(wm + mt * 16 + m16) * 32 + q4 * 8];
        #pragma unroll
        for (int nt = 0; nt < 4; nt++)
            bfr[nt] = *(const bf8_t*)&Bs[(wn + nt * 16 + m16) * 32 + q4 * 8];
        #pragma unroll
        for (int mt = 0; mt < 4; mt++)
            #pragma unroll
            for (int nt = 0; nt < 4; nt++)
                acc[mt][nt] = mfma16x32(af[mt], bfr[nt], acc[mt][nt]);
        __syncthreads();
    }

    #pragma unroll
    for (int nt = 0; nt < 4; nt++) {
        int cg = col0 + wn + nt * 16 + m16;
        float bv = bias[cg];
        #pragma unroll
        for (int mt = 0; mt < 4; mt++) {
            #pragma unroll
            for (int r = 0; r < 4; r++) {
                int rg = row0 + wm + mt * 16 + q4 * 4 + r;
                float v = acc[mt][nt][r] + bv;
                if constexpr (BF16_OUT)
                    ((__hip_bfloat16*)Cout)[(long)rg * ldc + cg] = __float2bfloat16(v);
                else
                    ((float*)Cout)[(long)rg * ldc + cg] = v;
            }
        }
    }
}

// ---------------- 256x256 8-PHASE pipelined NT GEMM for QKV ----------------
// Round-11: port to the m201-style 8-phase schedule. Round-10 structure was the
// 2-barrier-per-K-step class (~780 TF, its documented ceiling ~900): the whole
// stage+vmcnt+barrier cost serializes once per K-tile. Here each K-tile = 4 phases
// of {ds-read subtile || stage 1 half-tile (2 gl_lds) -> barrier -> 16 MFMA
// (setprio) -> barrier}; tile kt+1's 4 half-tiles issue at phases (kt-1,3)..(kt,2)
// (A-parts first: HBM-heavy; B-panel is L2-resident) and the only wait is a counted
// vmcnt(2) at phase 3 — never 0 in steady state. Hazards verified:
//  (a) write->vmcnt(2)+barrier->read: kt+1's 8 loads landed at (kt,3) checkpoint;
//  (b) read->barrier->overwrite: tile kt's last ds_reads (phase 2) drain before
//      phase-2's end barrier; same-dbuf writes (tile kt+2) start at (kt,3);
//  (c) stages during (kt,0..2) target dbuf (kt+1)&1, whose readers (tile kt-1)
//      finished before (kt-1,2)'s end barrier.
__global__ __launch_bounds__(512, 2) void gemm256(
    const __hip_bfloat16* __restrict__ A, const __hip_bfloat16* __restrict__ Bw,
    const float* __restrict__ bias, __hip_bfloat16* __restrict__ Cout,
    __hip_bfloat16* __restrict__ vtout, int Tdim,
    int M, int N, int K, int ldc)
{
    __shared__ __align__(16) __hip_bfloat16 Ah[2][2][128 * 64];  // [dbuf][half] 4x16KB
    __shared__ __align__(16) __hip_bfloat16 Bh[2][2][128 * 64];  // [dbuf][half] 4x16KB

    const int t = threadIdx.x;
    const int wv = t >> 6, ln = t & 63;
    const int m16 = ln & 15, q4 = ln >> 4;
    const int wr = wv >> 2, wc = wv & 3;   // 2 x 4 wave grid

    const int gx = N >> 8;
    const int nwg = gridDim.x;
    const int id = blockIdx.x;
    const int swz = ((nwg & 7) == 0) ? (id & 7) * (nwg >> 3) + (id >> 3) : id;  // T1 (bijective: nwg%8==0)
    const int col0 = (swz % gx) << 8;
    const int row0 = (swz / gx) << 8;

    const int NT = K >> 6;   // K-tiles of 64

    // stage one 128x64 half-tile (16 KB): linear LDS dest, inverse-swizzled src.
    // part: 0=A-half0, 1=A-half1, 2=B-half0, 3=B-half1 (A first: HBM slack).
    auto stage_part = [&](int kt, int part) {
        const __hip_bfloat16* src;
        __hip_bfloat16* dst;
        if (part < 2) {
            src = A + (size_t)(row0 + part * 128) * K + (size_t)kt * 64;
            dst = &Ah[kt & 1][part][0];
        } else {
            src = Bw + (size_t)(col0 + (part - 2) * 128) * K + (size_t)kt * 64;
            dst = &Bh[kt & 1][part - 2][0];
        }
        #pragma unroll
        for (int i = 0; i < 2; i++) {
            int s = i * 512 + t;
            int r = s >> 3, c = (s & 7) ^ (r & 7);
            gl_lds16(src + (size_t)r * K + c * 8,
                     (char*)dst + (size_t)(i * 512 + wv * 64) * 16);
        }
    };

    // prologue: tile 0 (all 4 parts) + tile 1 part0; vmcnt(2) = tile 0 landed.
    stage_part(0, 0); stage_part(0, 1); stage_part(0, 2); stage_part(0, 3);
    if (NT > 1) {
        stage_part(1, 0);
        asm volatile("s_waitcnt vmcnt(2)" ::: "memory");
    } else {
        asm volatile("s_waitcnt vmcnt(0)" ::: "memory");
    }
    __builtin_amdgcn_s_barrier();

    f4_t acc[8][4] = {};

    for (int kt = 0; kt < NT; kt++) {
        const __hip_bfloat16* Ab = &Ah[kt & 1][wr][0];        // wave's A-half
        const __hip_bfloat16* Bb = &Bh[kt & 1][wc >> 1][0];   // wave's B-half
        const int bc0 = (wc & 1) * 64;                         // col base in half

        auto lda = [&](const __hip_bfloat16* base, int r, int kc) {
            return *(const bf8_t*)&base[r * 64 + ((((kc << 2) | q4) ^ (r & 7)) << 3)];
        };

        bf8_t af[4][2], bf0[2][2], bf1[2][2];

        // ---- phase 0: ds-read af0 (8) + bf0 (4); stage part1 of kt+1
        #pragma unroll
        for (int mt = 0; mt < 4; mt++)
            #pragma unroll
            for (int kc = 0; kc < 2; kc++)
                af[mt][kc] = lda(Ab, mt * 16 + m16, kc);
        #pragma unroll
        for (int nt = 0; nt < 2; nt++)
            #pragma unroll
            for (int kc = 0; kc < 2; kc++)
                bf0[nt][kc] = lda(Bb, bc0 + nt * 16 + m16, kc);
        if (kt + 1 < NT) stage_part(kt + 1, 1);
        asm volatile("s_waitcnt lgkmcnt(8)" ::: "memory");   // partial drain (12 reads)
        __builtin_amdgcn_s_barrier();
        __builtin_amdgcn_s_setprio(1);
        #pragma unroll
        for (int mt = 0; mt < 4; mt++)
            #pragma unroll
            for (int nt = 0; nt < 2; nt++)
                #pragma unroll
                for (int kc = 0; kc < 2; kc++)
                    acc[mt][nt] = mfma16x32(af[mt][kc], bf0[nt][kc], acc[mt][nt]);
        __builtin_amdgcn_s_setprio(0);
        __builtin_amdgcn_s_barrier();

        // ---- phase 1: ds-read bf1 (4); stage part2 of kt+1
        #pragma unroll
        for (int nt = 0; nt < 2; nt++)
            #pragma unroll
            for (int kc = 0; kc < 2; kc++)
                bf1[nt][kc] = lda(Bb, bc0 + (2 + nt) * 16 + m16, kc);
        if (kt + 1 < NT) stage_part(kt + 1, 2);
        __builtin_amdgcn_s_barrier();
        __builtin_amdgcn_s_setprio(1);
        #pragma unroll
        for (int mt = 0; mt < 4; mt++)
            #pragma unroll
            for (int nt = 0; nt < 2; nt++)
                #pragma unroll
                for (int kc = 0; kc < 2; kc++)
                    acc[mt][2 + nt] = mfma16x32(af[mt][kc], bf1[nt][kc], acc[mt][2 + nt]);
        __builtin_amdgcn_s_setprio(0);
        __builtin_amdgcn_s_barrier();

        // ---- phase 2: ds-read af1 (8, reuse regs); stage part3 of kt+1
        #pragma unroll
        for (int mt = 0; mt < 4; mt++)
            #pragma unroll
            for (int kc = 0; kc < 2; kc++)
                af[mt][kc] = lda(Ab, (4 + mt) * 16 + m16, kc);
        if (kt + 1 < NT) stage_part(kt + 1, 3);
        __builtin_amdgcn_s_barrier();
        __builtin_amdgcn_s_setprio(1);
        #pragma unroll
        for (int mt = 0; mt < 4; mt++)
            #pragma unroll
            for (int nt = 0; nt < 2; nt++)
                #pragma unroll
                for (int kc = 0; kc < 2; kc++)
                    acc[4 + mt][2 + nt] = mfma16x32(af[mt][kc], bf1[nt][kc], acc[4 + mt][2 + nt]);
        __builtin_amdgcn_s_setprio(0);
        __builtin_amdgcn_s_barrier();

        // ---- phase 3: no ds-reads; stage part0 of kt+2; counted vmcnt checkpoint
        if (kt + 2 < NT) stage_part(kt + 2, 0);
        if (kt + 1 < NT) {
            if (kt + 2 < NT)
                asm volatile("s_waitcnt vmcnt(2)" ::: "memory");  // kt+1 landed; kt+2p0 in flight
            else
                asm volatile("s_waitcnt vmcnt(0)" ::: "memory");  // drain last tile
        }
        __builtin_amdgcn_s_barrier();
        __builtin_amdgcn_s_setprio(1);
        #pragma unroll
        for (int mt = 0; mt < 4; mt++)
            #pragma unroll
            for (int nt = 0; nt < 2; nt++)
                #pragma unroll
                for (int kc = 0; kc < 2; kc++)
                    acc[4 + mt][nt] = mfma16x32(af[mt][kc], bf0[nt][kc], acc[4 + mt][nt]);
        __builtin_amdgcn_s_setprio(0);
        if (kt + 1 < NT) __builtin_amdgcn_s_barrier();
    }

    if (col0 >= 2 * E_DIM) {
        // V block: write transposed into vt, 8B bf4 per (mt,nt) (4 consecutive tokens)
        #pragma unroll
        for (int nt = 0; nt < 4; nt++) {
            int cg = col0 + wc * 64 + nt * 16 + m16;
            float bval = bias[cg];
            int vrow = cg - 2 * E_DIM;
            #pragma unroll
            for (int mt = 0; mt < 8; mt++) {
                int rg0 = row0 + wr * 128 + mt * 16 + q4 * 4;
                f4_t vv;
                #pragma unroll
                for (int r = 0; r < 4; r++) vv[r] = acc[mt][nt][r] + bval;
                *(bf4_t*)&vtout[(long)vrow * Tdim + rg0] = pk4(vv);
            }
        }
    } else {
        #pragma unroll
        for (int nt = 0; nt < 4; nt++) {
            int cg = col0 + wc * 64 + nt * 16 + m16;
            float bval = bias[cg];
            #pragma unroll
            for (int mt = 0; mt < 8; mt++) {
                #pragma unroll
                for (int r = 0; r < 4; r++) {
                    int rg = row0 + wr * 128 + mt * 16 + q4 * 4 + r;
                    Cout[(long)rg * ldc + cg] = __float2bfloat16(acc[mt][nt][r] + bval);
                }
            }
        }
    }
}

// ---------------- RoPE (in place on q,k sections of qkv) ----------------
// HW trig in revolutions domain (v_sin/v_cos + fract range-reduction, scratch-free).
__global__ __launch_bounds__(256) void rope_kernel(
    __hip_bfloat16* __restrict__ qkv, const int* __restrict__ cu, int B, int T)
{
    long idx = (long)blockIdx.x * 256 + threadIdx.x;
    int i = idx & 31;
    long r = idx >> 5;
    int h = (int)(r % NHEADS);
    int tok = (int)(r / NHEADS);
    if (tok >= T) return;
    int pos = tok;
    for (int b = 1; b <= B; b++) if (tok >= cu[b]) pos = tok - cu[b];
    // revolutions per position: exp2(-i*log2(10000)/32 - log2(2*pi))
    float rev = (float)pos * exp2f(-(float)i * 0.41524100558003436f
                                   - 2.6514961294723187f);
    rev = rev - floorf(rev);
    float s, c;
    asm("v_sin_f32 %0, %1" : "=v"(s) : "v"(rev));
    asm("v_cos_f32 %0, %1" : "=v"(c) : "v"(rev));
    long base = (long)tok * QKV_LD + h * HDIM + i;
    {
        float q1 = __bfloat162float(qkv[base]);
        float q2 = __bfloat162float(qkv[base + 32]);
        qkv[base]      = __float2bfloat16(q1 * c - q2 * s);
        qkv[base + 32] = __float2bfloat16(q2 * c + q1 * s);
    }
    {
        long kb = base + E_DIM;
        float k1 = __bfloat162float(qkv[kb]);
        float k2 = __bfloat162float(qkv[kb + 32]);
        qkv[kb]      = __float2bfloat16(k1 * c - k2 * s);
        qkv[kb + 32] = __float2bfloat16(k2 * c + k1 * s);
    }
}

// ---------------- flash attention: round-7 structure (KVBLK=64, 2-phase, 4 blk/CU,
// longest-first). Byte-identical for clean attribution. ----
__global__ __launch_bounds__(256, 4) void attn_kernel(
    const __hip_bfloat16* __restrict__ qkv, const __hip_bfloat16* __restrict__ vt,
    const int* __restrict__ cu, __hip_bfloat16* __restrict__ obuf, int B, int T)
{
    __shared__ __align__(16) __hip_bfloat16 Ks[2][64 * 64];  // [key][d] swizzled, 2x8 KB
    __shared__ __align__(16) __hip_bfloat16 Vs[2][64 * 64];  // [d][key] swizzled, 2x8 KB

    int idx = blockIdx.x;
    int h = idx % NHEADS;
    int gt = idx / NHEADS;
    // longest-first: sequences sorted ascending in cu -> scan in REVERSE
    int b = B - 1, l = 0, seq0 = 0;
    for (; b >= 0; --b) {
        seq0 = cu[b];
        l = cu[b + 1] - seq0;
        int ntile = (l + 127) >> 7;
        if (gt < ntile) break;
        gt -= ntile;
    }
    if (b < 0) return;
    int q0 = gt * 128;
    const int NT = (l + 63) >> 6;

    const int t = threadIdx.x;
    const int wv = t >> 6, ln = t & 63;
    const int m16 = ln & 15, q4 = ln >> 4;

    // K: slot s2 -> key s2>>3, chunk (s2&7)^(key&7); V: d s2>>3, chunk (s2&7)^(d&7)
    auto stage_full = [&](int kv0n, int bi) {
        #pragma unroll
        for (int i = 0; i < 2; i++) {
            int s2 = i * 256 + t;
            int key = s2 >> 3, cg = (s2 & 7) ^ (key & 7);
            gl_lds16(qkv + (long)(seq0 + kv0n + key) * QKV_LD + E_DIM + h * HDIM + cg * 8,
                     (char*)&Ks[bi][0] + (size_t)(i * 256 + wv * 64) * 16);
        }
        #pragma unroll
        for (int i = 0; i < 2; i++) {
            int s2 = i * 256 + t;
            int d = s2 >> 3, cg = (s2 & 7) ^ (d & 7);
            gl_lds16(vt + (long)(h * HDIM + d) * T + seq0 + kv0n + cg * 8,
                     (char*)&Vs[bi][0] + (size_t)(i * 256 + wv * 64) * 16);
        }
    };
    auto stage_tail = [&](int kv0n, int bi) {   // dead in this workload (l % 128 == 0)
        #pragma unroll
        for (int i = 0; i < 2; i++) {
            int s2 = i * 256 + t;
            int key = s2 >> 3, c = s2 & 7;
            bf8_t v = (bf8_t)0;
            if (kv0n + key < l)
                v = *(const bf8_t*)(qkv + (long)(seq0 + kv0n + key) * QKV_LD + E_DIM + h * HDIM + c * 8);
            *(bf8_t*)&Ks[bi][key * 64 + (c ^ (key & 7)) * 8] = v;
        }
        #pragma unroll
        for (int i = 0; i < 2; i++) {
            int s2 = i * 256 + t;
            int d = s2 >> 3, c = s2 & 7;
            bf8_t v = (bf8_t)0;
            int tb = kv0n + c * 8;
            #pragma unroll
            for (int u = 0; u < 8; u++)
                if (tb + u < l)
                    v[u] = *(const short*)&vt[(long)(h * HDIM + d) * T + seq0 + tb + u];
            *(bf8_t*)&Vs[bi][d * 64 + (c ^ (d & 7)) * 8] = v;
        }
    };

    // prologue: issue staging of tile 0 first, then load Q while it flies
    if (64 <= l) stage_full(0, 0); else stage_tail(0, 0);

    // Q B-frags in registers: bq[nt][kc] = B[k=kc*32+q4*8+j][n=m16]
    bf8_t bq[2][2];
    #pragma unroll
    for (int nt = 0; nt < 2; nt++) {
        int qrow = q0 + wv * 32 + nt * 16 + m16;
        #pragma unroll
        for (int kc = 0; kc < 2; kc++) {
            bf8_t v = (bf8_t)0;
            if (qrow < l)
                v = *(const bf8_t*)(qkv + (long)(seq0 + qrow) * QKV_LD + h * HDIM + kc * 32 + q4 * 8);
            bq[nt][kc] = v;
        }
    }

    f4_t oacc[2][4] = {};
    float m_s[2] = {-1e30f, -1e30f};
    float l_s[2] = {0.0f, 0.0f};

    const int ksw0 = (q4 ^ (m16 & 7)) * 8;        // slot of global chunk q4
    const int ksw1 = ((4 + q4) ^ (m16 & 7)) * 8;  // slot of global chunk 4+q4

    asm volatile("s_waitcnt vmcnt(0) lgkmcnt(0)" ::: "memory");
    __builtin_amdgcn_s_barrier();

    for (int it = 0; it < NT; ++it) {
        const int kv0 = it << 6;
        const bool full = (kv0 + 64 <= l);
        if (it + 1 < NT) {                       // issue next tile's loads NOW
            int kvn = kv0 + 64;
            if (kvn + 64 <= l) stage_full(kvn, (it + 1) & 1);
            else stage_tail(kvn, (it + 1) & 1);
        }
        const __hip_bfloat16* Kb = Ks[it & 1];
        const __hip_bfloat16* Vb = Vs[it & 1];

        // S^T = K.Q^T : S[nt][mt] holds S^T[key=mt*16+q4*4+r][qrow=m16]
        f4_t S[2][4];
        __builtin_amdgcn_s_setprio(1);
        #pragma unroll
        for (int mt = 0; mt < 4; mt++) {
            const __hip_bfloat16* krow = &Kb[(mt * 16 + m16) * 64];
            bf8_t ak0 = *(const bf8_t*)(krow + ksw0);
            bf8_t ak1 = *(const bf8_t*)(krow + ksw1);
            #pragma unroll
            for (int nt = 0; nt < 2; nt++) {
                f4_t a = {};
                a = mfma16x32(ak0, bq[nt][0], a);
                a = mfma16x32(ak1, bq[nt][1], a);
                S[nt][mt] = a;
            }
        }
        __builtin_amdgcn_s_setprio(0);

        if (!full) {
            #pragma unroll
            for (int mt = 0; mt < 4; mt++) {
                #pragma unroll
                for (int r = 0; r < 4; r++) {
                    bool valid = (kv0 + mt * 16 + q4 * 4 + r) < l;
                    #pragma unroll
                    for (int nt = 0; nt < 2; nt++)
                        if (!valid) S[nt][mt][r] = -1e30f;
                }
            }
        }

        // online softmax (base-2 domain; log2e folded into Wq/bq) + defer-max (THR=8)
        // tree reductions: fmax depth 4, ls partials depth ~6
        #pragma unroll
        for (int nt = 0; nt < 2; nt++) {
            float pm[4];
            #pragma unroll
            for (int mt = 0; mt < 4; mt++)
                pm[mt] = fmaxf(fmaxf(S[nt][mt][0], S[nt][mt][1]),
                               fmaxf(S[nt][mt][2], S[nt][mt][3]));
            float mx = fmaxf(fmaxf(pm[0], pm[1]), fmaxf(pm[2], pm[3]));
            mx = fmaxf(mx, __shfl_xor(mx, 16));
            mx = fmaxf(mx, __shfl_xor(mx, 32));
            if (!__all(mx - m_s[nt] <= 8.0f)) {
                float mn = fmaxf(m_s[nt], mx);
                float al = exp2f(m_s[nt] - mn);
                m_s[nt] = mn;
                l_s[nt] *= al;
                #pragma unroll
                for (int dt = 0; dt < 4; dt++)
                    #pragma unroll
                    for (int r = 0; r < 4; r++)
                        oacc[nt][dt][r] *= al;
            }
            float mcur = m_s[nt];
            float ps[4];
            #pragma unroll
            for (int mt = 0; mt < 4; mt++) {
                f4_t p;
                p[0] = exp2f(S[nt][mt][0] - mcur);
                p[1] = exp2f(S[nt][mt][1] - mcur);
                p[2] = exp2f(S[nt][mt][2] - mcur);
                p[3] = exp2f(S[nt][mt][3] - mcur);
                S[nt][mt] = p;
                ps[mt] = (p[0] + p[1]) + (p[2] + p[3]);
            }
            l_s[nt] += (ps[0] + ps[1]) + (ps[2] + ps[3]);
        }

        // O^T += V^T . P^T  (A=V^T from swizzled LDS, B=P^T packed in-place)
        __builtin_amdgcn_s_setprio(1);
        #pragma unroll
        for (int mt = 0; mt < 4; mt++) {
            bf4_t bp0 = pk4(S[0][mt]);
            bf4_t bp1 = pk4(S[1][mt]);
            const int vsw = ((mt * 2 + (q4 >> 1)) ^ (m16 & 7)) * 8 + (q4 & 1) * 4;
            #pragma unroll
            for (int dt = 0; dt < 4; dt++) {
                bf4_t av = *(const bf4_t*)&Vb[(dt * 16 + m16) * 64 + vsw];
                oacc[0][dt] = mfma16x16(av, bp0, oacc[0][dt]);
                oacc[1][dt] = mfma16x16(av, bp1, oacc[1][dt]);
            }
        }
        __builtin_amdgcn_s_setprio(0);

        if (it + 1 < NT) {
            // wait for next tile's staging (issued before compute -> mostly landed)
            // and make all waves' LDS writes visible; ONE barrier per tile.
            asm volatile("s_waitcnt vmcnt(0) lgkmcnt(0)" ::: "memory");
            __builtin_amdgcn_s_barrier();
        }
    }

    // finalize
    #pragma unroll
    for (int nt = 0; nt < 2; nt++) {
        float ls = l_s[nt];
        ls += __shfl_xor(ls, 16);
        ls += __shfl_xor(ls, 32);
        float inv = 1.0f / ls;
        int qrow = q0 + wv * 32 + nt * 16 + m16;
        if (qrow < l) {
            #pragma unroll
            for (int dt = 0; dt < 4; dt++) {
                f4_t o;
                #pragma unroll
                for (int r = 0; r < 4; r++)
                    o[r] = oacc[nt][dt][r] * inv;
                *(bf4_t*)&obuf[(long)(seq0 + qrow) * E_DIM + h * HDIM + dt * 16 + q4 * 4] = pk4(o);
            }
        }
    }
}

// ---------------- launch ----------------
extern "C" void kernel_launch(void* const* d_in, const int* in_sizes, int n_in,
                              void* d_out, int out_size, void* d_ws, size_t ws_size,
                              hipStream_t stream) {
    const int E = E_DIM;
    const int T = in_sizes[0] / E;      // 8192
    const int B = in_sizes[1] - 1;      // 8

    const float* x  = (const float*)d_in[0];
    const int*   cu = (const int*)d_in[1];
    const float* Wq = (const float*)d_in[3];
    const float* bq = (const float*)d_in[4];
    const float* Wk = (const float*)d_in[5];
    const float* bk = (const float*)d_in[6];
    const float* Wv = (const float*)d_in[7];
    const float* bv = (const float*)d_in[8];
    const float* Wo = (const float*)d_in[9];
    const float* bo = (const float*)d_in[10];

    char* ws = (char*)d_ws;
    size_t off = 0;
    auto alloc = [&](size_t bytes) -> void* {
        void* p = ws + off;
        off = (off + bytes + 255) & ~(size_t)255;
        return p;
    };
    __hip_bfloat16* xbf   = (__hip_bfloat16*)alloc((size_t)T * E * 2);
    __hip_bfloat16* wqkv  = (__hip_bfloat16*)alloc((size_t)3 * E * E * 2);
    __hip_bfloat16* wobf  = (__hip_bfloat16*)alloc((size_t)E * E * 2);
    float*          bqkv  = (float*)alloc((size_t)3 * E * 4);
    __hip_bfloat16* qkvb  = (__hip_bfloat16*)alloc((size_t)T * 3 * E * 2);
    __hip_bfloat16* vt    = (__hip_bfloat16*)alloc((size_t)E * T * 2);
    __hip_bfloat16* obuf  = xbf;  // alias: x_bf dead after QKV GEMM

    long nx8 = (long)T * E / 8;
    long nw8 = (long)E * E / 8;
    long nb8 = (long)3 * E / 8;
    long total = nx8 + 4 * nw8 + nb8;
    int pblocks = (int)((total + 255) / 256);
    prep_kernel<<<pblocks, 256, 0, stream>>>(x, Wq, Wk, Wv, Wo, bq, bk, bv,
                                             xbf, wqkv, wobf, bqkv, nx8, nw8, nb8);

    // QKV projection: 256^2-tile 8-phase pipelined GEMM; V columns -> vt transposed
    gemm256<<<(T / 256) * (3 * E / 256), 512, 0, stream>>>(
        xbf, wqkv, bqkv, qkvb, vt, T, T, 3 * E, E, 3 * E);

    // standalone RoPE with HW trig (scratch-free)
    rope_kernel<<<(int)(((long)T * NHEADS * 32) / 256), 256, 0, stream>>>(qkvb, cu, B, T);

    // 128-row q-tiles: upper bound on sum of per-seq ceil(l/128)
    int qtiles_ub = T / 128 + B;
    attn_kernel<<<qtiles_ub * NHEADS, 256, 0, stream>>>(qkvb, vt, cu, obuf, B, T);

    // output projection: N=1280 -> only 160 blocks at 256^2; keep 128^2 (640 blocks)
    gemm_nt<false><<<dim3(E / 128, T / 128), 256, 0, stream>>>(
        obuf, wobf, bo, d_out, T, E, E, E);
}